// Round 12
// baseline (83.210 us; speedup 1.0000x reference)
//
#include <hip/hip_runtime.h>
#include <stdint.h>

#define NB 8192
#define DD 256

typedef unsigned short ushort_t;
typedef __attribute__((ext_vector_type(8))) short bf16x8;
typedef __attribute__((ext_vector_type(4))) float f32x4;

// ==================== workspace layout (10039296 B <= proven 10092544) ====================
#define OFF_DIAG   0          // f32[8192]
#define OFF_NEG    32768      // int[8192]
#define OFF_MROWS  65536      // int[1024]
#define OFF_ACC    69632      // f32 acc @+0, int mcount @+4
#define OFF_BP1    73728      // u16[8][8192]   (128 KB)
#define OFF_BP2    204800     // u16[64][1024]  (128 KB)
#define OFF_FB2    335872     // u64[64][1024]  (512 KB) -> ends 860160
#define OFF_DIAG2  860160     // f32[1024]
#define OFF_A2     864256     // bf16[1024][256] (512 KB, swizzled by slot)
#define OFF_W1T    1388544    // bf16[256][512]  (256 KB, swizzled)
#define OFF_TB     1650688    // bf16[8192][256] (4 MB, swizzled)
#define OFF_VB     5844992    // bf16[8192][256] (4 MB, swizzled) -> end 10039296

__device__ __forceinline__ unsigned short f2bf(float x) {
    uint32_t u = __float_as_uint(x);
    return (unsigned short)((u + 0x7FFFu + ((u >> 16) & 1u)) >> 16);
}

__device__ __forceinline__ uint4 packbf8(float4 x, float4 y) {
    uint4 o;
    o.x = (uint32_t)f2bf(x.x) | ((uint32_t)f2bf(x.y) << 16);
    o.y = (uint32_t)f2bf(x.z) | ((uint32_t)f2bf(x.w) << 16);
    o.z = (uint32_t)f2bf(y.x) | ((uint32_t)f2bf(y.y) << 16);
    o.w = (uint32_t)f2bf(y.z) | ((uint32_t)f2bf(y.w) << 16);
    return o;
}

__device__ __forceinline__ unsigned fkey(float s) {
    unsigned u = __float_as_uint(s);
    return (u & 0x80000000u) ? ~u : (u | 0x80000000u);
}

// ---------------- prep_uni: cvt uni (swizzled), diag, W1T, zero-init ----------------
__global__ __launch_bounds__(256) void prep_uni_kernel(const float* __restrict__ t,
                                                       const float* __restrict__ v,
                                                       const float* __restrict__ W1,
                                                       ushort_t* __restrict__ tb,
                                                       ushort_t* __restrict__ vb,
                                                       ushort_t* __restrict__ W1T,
                                                       float* __restrict__ diag,
                                                       uint32_t* __restrict__ zeroRegion) {
    const int b = blockIdx.x;
    const int tid = threadIdx.x;
    if (b < 2048) {
        const float* in = (b < 1024) ? t : v;
        ushort_t* out = (b < 1024) ? tb : vb;
        int i = (b & 1023) * 256 + tid;             // 16B-chunk id
        int row = i >> 5, cw = i & 31, kb = cw >> 3, c = cw & 7;
        int csrc = c ^ (row & 7);
        const float4* src = (const float4*)(in + (size_t)row * DD + kb * 64 + csrc * 8);
        ((uint4*)out)[i] = packbf8(src[0], src[1]);
    } else if (b < 4096) {
        if (b == 2048 && tid < 2) zeroRegion[tid] = 0;   // acc + mcount
        int row = (b - 2048) * 4 + (tid >> 6);
        int lane = tid & 63;
        float4 a = *(const float4*)(t + (size_t)row * DD + lane * 4);
        float4 bb = *(const float4*)(v + (size_t)row * DD + lane * 4);
        float s = a.x * bb.x + a.y * bb.y + a.z * bb.z + a.w * bb.w;
        #pragma unroll
        for (int off = 32; off; off >>= 1) s += __shfl_down(s, off);
        if (lane == 0) diag[row] = s;
    } else {
        // W1T[n][k] = bf16(W1[k][n]), chunk-swizzled by n&7 within each 64-k block
        __shared__ float Ls[64][68];
        int tt = b - 4096;                          // 0..31
        int kb = tt >> 2, nb = tt & 3;
        int r = tid >> 2, q4 = tid & 3;
        #pragma unroll
        for (int j = 0; j < 4; j++) {
            float4 x = *(const float4*)(W1 + (size_t)(kb * 64 + r) * DD + nb * 64 + q4 * 16 + j * 4);
            *(float4*)&Ls[r][q4 * 16 + j * 4] = x;
        }
        __syncthreads();
        int rn = tid >> 2, cq = (tid & 3) * 2;
        #pragma unroll
        for (int cc = 0; cc < 2; cc++) {
            int c = cq + cc;
            int csrc = c ^ (rn & 7);
            float4 x, y;
            x.x = Ls[csrc * 8 + 0][rn]; x.y = Ls[csrc * 8 + 1][rn];
            x.z = Ls[csrc * 8 + 2][rn]; x.w = Ls[csrc * 8 + 3][rn];
            y.x = Ls[csrc * 8 + 4][rn]; y.y = Ls[csrc * 8 + 5][rn];
            y.z = Ls[csrc * 8 + 6][rn]; y.w = Ls[csrc * 8 + 7][rn];
            *(uint4*)&W1T[(size_t)(nb * 64 + rn) * 512 + kb * 64 + c * 8] = packbf8(x, y);
        }
    }
}

// ---------------- shared B-staging (proven R7) ----------------
__device__ __forceinline__ void stage_b(const ushort_t* __restrict__ VB, ushort_t* Bs,
                                        int colBase, int kc, int tid) {
    #pragma unroll
    for (int i = 0; i < 4; ++i) {
        int idx = i * 256 + tid;              // 0..1023
        int r = idx >> 3, c8 = idx & 7;       // source pre-swizzled -> linear copy
        __builtin_amdgcn_global_load_lds(
            (const __attribute__((address_space(1))) uint32_t*)(VB + (size_t)(colBase + r) * DD + kc + c8 * 8),
            (__attribute__((address_space(3))) uint32_t*)(Bs + idx * 8), 16, 0, 0);
    }
}

// ---------------- mine_p1: prefix cols [0,1024) (proven R9) ----------------
__global__ __launch_bounds__(256, 4) void mine_p1_kernel(const ushort_t* __restrict__ TB,
                                                         const ushort_t* __restrict__ VB,
                                                         const float* __restrict__ diag,
                                                         ushort_t* __restrict__ bp1) {
    __shared__ ushort_t Bs[2][128 * 64];       // 32 KB
    __shared__ float diag_s[128];

    const int tid = threadIdx.x;
    const int rowBase = blockIdx.x * 128;
    const int colBase = blockIdx.y * 128;      // y < 8
    const int lane = tid & 63;
    const int wave = tid >> 6;
    const int wr = wave >> 1, wc = wave & 1;
    const int lo = lane & 15, hi = lane >> 4;
    const int lx = lo & 7;

    if (tid < 128) diag_s[tid] = diag[rowBase + tid];

    f32x4 acc[4][4];
    #pragma unroll
    for (int m = 0; m < 4; m++)
        #pragma unroll
        for (int n = 0; n < 4; n++) acc[m][n] = (f32x4){0.f, 0.f, 0.f, 0.f};

    const ushort_t* Abase = TB + (size_t)(rowBase + wr * 64 + lo) * DD;

    stage_b(VB, Bs[0], colBase, 0, tid);
    __syncthreads();

    for (int kt = 0; kt < 4; ++kt) {
        const int buf = kt & 1;
        if (kt < 3)
            stage_b(VB, Bs[buf ^ 1], colBase, (kt + 1) * 64, tid);
        #pragma unroll
        for (int ksl = 0; ksl < 2; ksl++) {
            const int ch = ((((ksl << 2) | hi) ^ lx) << 3);
            bf16x8 a[4], b[4];
            #pragma unroll
            for (int m = 0; m < 4; m++)
                a[m] = *(const bf16x8*)(Abase + (size_t)m * 16 * DD + kt * 64 + ch);
            #pragma unroll
            for (int n = 0; n < 4; n++)
                b[n] = *(const bf16x8*)&Bs[buf][(wc * 64 + n * 16 + lo) * 64 + ch];
            #pragma unroll
            for (int m = 0; m < 4; m++)
                #pragma unroll
                for (int n = 0; n < 4; n++)
                    acc[m][n] = __builtin_amdgcn_mfma_f32_16x16x32_bf16(a[m], b[n], acc[m][n], 0, 0, 0);
        }
        __syncthreads();
    }

    #pragma unroll
    for (int m = 0; m < 4; m++) {
        #pragma unroll
        for (int q = 0; q < 4; q++) {
            const int rl = wr * 64 + m * 16 + hi * 4 + q;
            const int grow = rowBase + rl;
            const float c0 = diag_s[rl] - 0.35f;
            int bm = 0x7FFFFFFF;
            #pragma unroll
            for (int n = 0; n < 4; n++) {
                const float tt = acc[m][n][q] - c0;
                const int gcol = colBase + wc * 64 + n * 16 + lo;
                int cand = (fabsf(tt) < 0.15f && gcol != grow) ? gcol : 0x7FFFFFFF;
                bm = min(bm, cand);
            }
            #pragma unroll
            for (int off = 1; off < 16; off <<= 1) bm = min(bm, __shfl_xor(bm, off));
            if (lo == 0)
                bp1[blockIdx.y * NB + grow] = (ushort_t)min(bm, 0xFFFF);
        }
    }
}

// ---------------- combine_p1: prefix min; collect missing rows (cap 1024) ----------------
__global__ __launch_bounds__(256) void combine_p1_kernel(const ushort_t* __restrict__ bp1,
                                                         int* __restrict__ neg,
                                                         int* __restrict__ mrows,
                                                         int* __restrict__ mcount) {
    int row = blockIdx.x * 256 + threadIdx.x;
    int bmin = 0xFFFF;
    #pragma unroll
    for (int g = 0; g < 8; g++) bmin = min(bmin, (int)bp1[g * NB + row]);
    if (bmin < 0xFFFF) {
        neg[row] = bmin;
    } else {
        neg[row] = (row + 4096) & (NB - 1);     // placeholder, overwritten by combine_p2
        int i = atomicAdd(mcount, 1);
        if (i < 1024) mrows[i] = row;
    }
}

// ---------------- gather_p2: compact missing rows -> A2 (re-keyed swizzle), diag2 ----------------
__global__ __launch_bounds__(256) void gather_p2_kernel(const ushort_t* __restrict__ TB,
                                                        const float* __restrict__ diag,
                                                        const int* __restrict__ mrows,
                                                        const int* __restrict__ mcount,
                                                        ushort_t* __restrict__ A2,
                                                        float* __restrict__ diag2) {
    const int count = min(mcount[0], 1024);
    int idx = blockIdx.x * 256 + threadIdx.x;   // 16384 threads
    #pragma unroll
    for (int u = 0; u < 2; u++) {
        int t = idx * 2 + u;                    // chunk-copy id, 0..32767
        int s = t >> 5, c = t & 31;             // slot, 16B chunk
        int kb = c >> 3, cc = c & 7;
        uint4 val = {0, 0, 0, 0};
        if (s < count) {
            int r = mrows[s];
            int csrc = cc ^ ((s ^ r) & 7);      // re-key swizzle: tb keyed by r&7 -> A2 keyed by s&7
            val = *(const uint4*)(TB + (size_t)r * DD + kb * 64 + csrc * 8);
        }
        *(uint4*)(A2 + (size_t)s * DD + kb * 64 + cc * 8) = val;
    }
    if (idx < 1024) diag2[idx] = (idx < count) ? diag[mrows[idx]] : 0.f;
}

// ---------------- mine_p2: missing rows x all cols; band-min + argmax fallback ----------------
__global__ __launch_bounds__(256, 3) void mine_p2_kernel(const ushort_t* __restrict__ A2,
                                                         const ushort_t* __restrict__ VB,
                                                         const float* __restrict__ diag2,
                                                         const int* __restrict__ mrows,
                                                         const int* __restrict__ mcount,
                                                         ushort_t* __restrict__ bp2,
                                                         unsigned long long* __restrict__ fb2) {
    const int slotBase = blockIdx.x * 128;
    const int count = min(mcount[0], 1024);
    if (slotBase >= count) return;              // uniform early-out for inactive panels

    __shared__ ushort_t Bs[2][128 * 64];
    __shared__ float diag_s[128];
    __shared__ int rows_s[128];

    const int tid = threadIdx.x;
    const int colBase = blockIdx.y * 128;       // y < 64
    const int lane = tid & 63;
    const int wave = tid >> 6;
    const int wr = wave >> 1, wc = wave & 1;
    const int lo = lane & 15, hi = lane >> 4;
    const int lx = lo & 7;

    if (tid < 128) {
        diag_s[tid] = diag2[slotBase + tid];
        rows_s[tid] = mrows[slotBase + tid];    // garbage for pad slots; results discarded
    }

    f32x4 acc[4][4];
    #pragma unroll
    for (int m = 0; m < 4; m++)
        #pragma unroll
        for (int n = 0; n < 4; n++) acc[m][n] = (f32x4){0.f, 0.f, 0.f, 0.f};

    const ushort_t* Abase = A2 + (size_t)(slotBase + wr * 64 + lo) * DD;

    stage_b(VB, Bs[0], colBase, 0, tid);
    __syncthreads();

    for (int kt = 0; kt < 4; ++kt) {
        const int buf = kt & 1;
        if (kt < 3)
            stage_b(VB, Bs[buf ^ 1], colBase, (kt + 1) * 64, tid);
        #pragma unroll
        for (int ksl = 0; ksl < 2; ksl++) {
            const int ch = ((((ksl << 2) | hi) ^ lx) << 3);
            bf16x8 a[4], b[4];
            #pragma unroll
            for (int m = 0; m < 4; m++)
                a[m] = *(const bf16x8*)(Abase + (size_t)m * 16 * DD + kt * 64 + ch);
            #pragma unroll
            for (int n = 0; n < 4; n++)
                b[n] = *(const bf16x8*)&Bs[buf][(wc * 64 + n * 16 + lo) * 64 + ch];
            #pragma unroll
            for (int m = 0; m < 4; m++)
                #pragma unroll
                for (int n = 0; n < 4; n++)
                    acc[m][n] = __builtin_amdgcn_mfma_f32_16x16x32_bf16(a[m], b[n], acc[m][n], 0, 0, 0);
        }
        __syncthreads();
    }

    #pragma unroll
    for (int m = 0; m < 4; m++) {
        #pragma unroll
        for (int q = 0; q < 4; q++) {
            const int rl = wr * 64 + m * 16 + hi * 4 + q;
            const int actual = rows_s[rl];
            const float c0 = diag_s[rl] - 0.35f;
            int bm = 0x7FFFFFFF;
            unsigned long long pk = 0ULL;
            #pragma unroll
            for (int n = 0; n < 4; n++) {
                const float s = acc[m][n][q];
                const int gcol = colBase + wc * 64 + n * 16 + lo;
                if (gcol != actual) {
                    unsigned long long p = ((unsigned long long)fkey(s) << 32) | (unsigned)(NB - 1 - gcol);
                    pk = (p > pk) ? p : pk;
                    if (fabsf(s - c0) < 0.15f) bm = min(bm, gcol);
                }
            }
            #pragma unroll
            for (int off = 1; off < 16; off <<= 1) {
                unsigned long long po = __shfl_xor(pk, off);
                int bo = __shfl_xor(bm, off);
                pk = (po > pk) ? po : pk;
                bm = min(bm, bo);
            }
            if (lo == 0) {
                bp2[blockIdx.y * 1024 + slotBase + rl] = (ushort_t)min(bm, 0xFFFF);
                fb2[blockIdx.y * 1024 + slotBase + rl] = pk;
            }
        }
    }
}

// ---------------- combine_p2: finalize missing rows ----------------
__global__ __launch_bounds__(256) void combine_p2_kernel(const ushort_t* __restrict__ bp2,
                                                         const unsigned long long* __restrict__ fb2,
                                                         const int* __restrict__ mrows,
                                                         const int* __restrict__ mcount,
                                                         int* __restrict__ neg) {
    int s = blockIdx.x * 256 + threadIdx.x;
    const int count = min(mcount[0], 1024);
    if (s >= count) return;
    int bmin = 0xFFFF;
    unsigned long long pk = 0ULL;
    for (int g = 0; g < 64; g++) {
        bmin = min(bmin, (int)bp2[g * 1024 + s]);
        unsigned long long f = fb2[g * 1024 + s];
        pk = (f > pk) ? f : pk;
    }
    neg[mrows[s]] = (bmin < 0xFFFF) ? bmin : (NB - 1 - (int)(unsigned)(pk & 0xFFFFFFFFull));
}

// ---------------- prep_head: cvt tcross/vcross (swizzled) only ----------------
__global__ __launch_bounds__(256) void prep_head_kernel(const float* __restrict__ tcross,
                                                        const float* __restrict__ vcross,
                                                        ushort_t* __restrict__ tb,
                                                        ushort_t* __restrict__ vb) {
    const int b = blockIdx.x;
    const float* in = (b < 1024) ? tcross : vcross;
    ushort_t* out = (b < 1024) ? tb : vb;
    int i = (b & 1023) * 256 + threadIdx.x;
    int row = i >> 5, cw = i & 31, kb = cw >> 3, c = cw & 7;
    int csrc = c ^ (row & 7);
    const float4* src = (const float4*)(in + (size_t)row * DD + kb * 64 + csrc * 8);
    ((uint4*)out)[i] = packbf8(src[0], src[1]);
}

// ==================== MFMA ITM head: 32 rows/block, grid (256,2) — proven in R8 ====================
__device__ __forceinline__ void stage_head32(const ushort_t* __restrict__ TCB,
                                             const ushort_t* __restrict__ VCB,
                                             const int* __restrict__ neg, int isNeg,
                                             const ushort_t* __restrict__ W1T,
                                             ushort_t* As, ushort_t* Bs,
                                             int rowBase, int kc, int tid) {
    {                                             // A: 32 rows x 64 k (256 loads)
        int r = tid >> 3, c8 = tid & 7;
        const ushort_t* src;
        if (kc < 256) {
            src = TCB + (size_t)(rowBase + r) * DD + kc + c8 * 8;
        } else {
            int rr = isNeg ? neg[rowBase + r] : (rowBase + r);
            int cs = c8 ^ ((r ^ rr) & 7);          // re-key rr&7 -> r&7
            src = VCB + (size_t)rr * DD + (kc - 256) + cs * 8;
        }
        __builtin_amdgcn_global_load_lds(
            (const __attribute__((address_space(1))) uint32_t*)src,
            (__attribute__((address_space(3))) uint32_t*)(As + tid * 8), 16, 0, 0);
    }
    #pragma unroll
    for (int i = 0; i < 8; ++i) {                 // B: 256 cols x 64 k (W1T pre-swizzled)
        int idx = i * 256 + tid;
        int n = idx >> 3, c8 = idx & 7;
        __builtin_amdgcn_global_load_lds(
            (const __attribute__((address_space(1))) uint32_t*)(W1T + (size_t)n * 512 + kc + c8 * 8),
            (__attribute__((address_space(3))) uint32_t*)(Bs + idx * 8), 16, 0, 0);
    }
}

__global__ __launch_bounds__(256) void head3_kernel(const ushort_t* __restrict__ TCB,
                                                    const ushort_t* __restrict__ VCB,
                                                    const ushort_t* __restrict__ W1T,
                                                    const int* __restrict__ neg,
                                                    const float* __restrict__ tcf,
                                                    const float* __restrict__ vcf,
                                                    const float* __restrict__ W1,
                                                    const float* __restrict__ b1,
                                                    const float* __restrict__ W2,
                                                    const float* __restrict__ b2,
                                                    float* __restrict__ acc_out) {
    __shared__ ushort_t As[2][32 * 64];           // 4 KB x2
    __shared__ ushort_t Bs[2][256 * 64];          // 32 KB x2
    __shared__ float dot_l[32];
    __shared__ float logit_l[32];

    const int tid = threadIdx.x;
    const int rowBase = blockIdx.x * 32;
    const int isNeg = blockIdx.y;
    const int lane = tid & 63;
    const int wcv = tid >> 6;                     // wave = col group (4 x 64 cols)
    const int lo = lane & 15, hi = lane >> 4;
    const int lx = lo & 7;

    stage_head32(TCB, VCB, neg, isNeg, W1T, As[0], Bs[0], rowBase, 0, tid);

    // inline dot feature (fp32 exact): 8 threads per row
    {
        int r = tid >> 3, e = tid & 7;
        int grow = rowBase + r;
        int vrow = isNeg ? neg[grow] : grow;
        const float4* tp = (const float4*)(tcf + (size_t)grow * DD + e * 32);
        const float4* vp = (const float4*)(vcf + (size_t)vrow * DD + e * 32);
        float sd = 0.f;
        #pragma unroll
        for (int j = 0; j < 8; j++) {
            float4 a = tp[j], v = vp[j];
            sd += a.x * v.x + a.y * v.y + a.z * v.z + a.w * v.w;
        }
        sd += __shfl_xor(sd, 1);
        sd += __shfl_xor(sd, 2);
        sd += __shfl_xor(sd, 4);
        if (e == 0) dot_l[r] = sd;
        if (tid < 32) logit_l[tid] = 0.f;
    }

    f32x4 acc[2][4];
    #pragma unroll
    for (int m = 0; m < 2; m++)
        #pragma unroll
        for (int n = 0; n < 4; n++) acc[m][n] = (f32x4){0.f, 0.f, 0.f, 0.f};

    __syncthreads();

    for (int kt = 0; kt < 8; ++kt) {
        const int buf = kt & 1;
        if (kt < 7)
            stage_head32(TCB, VCB, neg, isNeg, W1T, As[buf ^ 1], Bs[buf ^ 1], rowBase, (kt + 1) * 64, tid);
        #pragma unroll
        for (int ksl = 0; ksl < 2; ksl++) {
            const int ch = ((((ksl << 2) | hi) ^ lx) << 3);
            bf16x8 a[2], b[4];
            #pragma unroll
            for (int m = 0; m < 2; m++)
                a[m] = *(const bf16x8*)&As[buf][(m * 16 + lo) * 64 + ch];
            #pragma unroll
            for (int n = 0; n < 4; n++)
                b[n] = *(const bf16x8*)&Bs[buf][(wcv * 64 + n * 16 + lo) * 64 + ch];
            #pragma unroll
            for (int m = 0; m < 2; m++)
                #pragma unroll
                for (int n = 0; n < 4; n++)
                    acc[m][n] = __builtin_amdgcn_mfma_f32_16x16x32_bf16(a[m], b[n], acc[m][n], 0, 0, 0);
        }
        __syncthreads();
    }

    float b1v[4], w5v[4], w2v[4];
    #pragma unroll
    for (int n = 0; n < 4; n++) {
        int cl = wcv * 64 + n * 16 + lo;
        b1v[n] = b1[cl];
        w5v[n] = W1[(size_t)512 * DD + cl];
        w2v[n] = W2[cl];
    }
    #pragma unroll
    for (int m = 0; m < 2; m++) {
        #pragma unroll
        for (int q = 0; q < 4; q++) {
            const int rl = m * 16 + hi * 4 + q;
            const float dt = dot_l[rl];
            float x = 0.f;
            #pragma unroll
            for (int n = 0; n < 4; n++) {
                float h = acc[m][n][q] + b1v[n] + dt * w5v[n];
                x += fmaxf(h, 0.f) * w2v[n];
            }
            #pragma unroll
            for (int off = 1; off < 16; off <<= 1) x += __shfl_xor(x, off);
            if (lo == 0) atomicAdd(&logit_l[rl], x);
        }
    }
    __syncthreads();

    if (tid < 32) {
        float x = logit_l[tid] + b2[0];
        float z = isNeg ? x : -x;                        // 1-sigmoid(x) = sigmoid(-x)
        float term = -logf(1.f / (1.f + expf(z)) + 1e-8f);
        #pragma unroll
        for (int off = 16; off; off >>= 1) term += __shfl_down(term, off);
        if (tid == 0) atomicAdd(acc_out, term);
    }
}

__global__ void finalize_kernel(const float* __restrict__ acc, float* __restrict__ out) {
    out[0] = acc[0] * (1.0f / (2.0f * (float)NB));
}

// ==================== launch ====================
extern "C" void kernel_launch(void* const* d_in, const int* in_sizes, int n_in,
                              void* d_out, int out_size, void* d_ws, size_t ws_size,
                              hipStream_t stream) {
    const float* vcross = (const float*)d_in[0];
    const float* tcross = (const float*)d_in[1];
    const float* vuni   = (const float*)d_in[2];
    const float* tuni   = (const float*)d_in[3];
    const float* W1     = (const float*)d_in[4];
    const float* b1     = (const float*)d_in[5];
    const float* W2     = (const float*)d_in[6];
    const float* b2     = (const float*)d_in[7];

    char* ws = (char*)d_ws;
    float* diag   = (float*)(ws + OFF_DIAG);
    int* neg      = (int*)(ws + OFF_NEG);
    int* mrows    = (int*)(ws + OFF_MROWS);
    float* acc    = (float*)(ws + OFF_ACC);
    int* mcount   = (int*)(ws + OFF_ACC + 4);
    ushort_t* bp1 = (ushort_t*)(ws + OFF_BP1);
    ushort_t* bp2 = (ushort_t*)(ws + OFF_BP2);
    unsigned long long* fb2 = (unsigned long long*)(ws + OFF_FB2);
    float* diag2  = (float*)(ws + OFF_DIAG2);
    ushort_t* A2  = (ushort_t*)(ws + OFF_A2);
    ushort_t* w1t = (ushort_t*)(ws + OFF_W1T);
    ushort_t* tb  = (ushort_t*)(ws + OFF_TB);
    ushort_t* vb  = (ushort_t*)(ws + OFF_VB);

    prep_uni_kernel<<<4128, 256, 0, stream>>>(tuni, vuni, W1, tb, vb, w1t, diag,
                                              (uint32_t*)(ws + OFF_ACC));
    mine_p1_kernel<<<dim3(64, 8), 256, 0, stream>>>(tb, vb, diag, bp1);
    combine_p1_kernel<<<NB / 256, 256, 0, stream>>>(bp1, neg, mrows, mcount);
    gather_p2_kernel<<<64, 256, 0, stream>>>(tb, diag, mrows, mcount, A2, diag2);
    mine_p2_kernel<<<dim3(8, 64), 256, 0, stream>>>(A2, vb, diag2, mrows, mcount, bp2, fb2);
    combine_p2_kernel<<<4, 256, 0, stream>>>(bp2, fb2, mrows, mcount, neg);
    prep_head_kernel<<<2048, 256, 0, stream>>>(tcross, vcross, tb, vb);
    head3_kernel<<<dim3(NB / 32, 2), 256, 0, stream>>>(tb, vb, w1t, neg, tcross, vcross,
                                                       W1, b1, W2, b2, acc);
    finalize_kernel<<<1, 1, 0, stream>>>(acc, (float*)d_out);
}

// Round 13
// 75.748 us; speedup vs baseline: 1.0985x; 1.0985x over previous
//
#include <hip/hip_runtime.h>
#include <stdint.h>

#define NB 8192
#define DD 256

typedef unsigned short ushort_t;
typedef __attribute__((ext_vector_type(8))) short bf16x8;
typedef __attribute__((ext_vector_type(4))) float f32x4;

// ==================== workspace layout ====================
// small path (<= proven 10039296); big path adds cross buffers (gated on ws_size)
#define OFF_DIAG   0          // f32[8192]
#define OFF_NEG    32768      // int[8192]
#define OFF_MROWS  65536      // int[1024]
#define OFF_ACC    69632      // f32 acc @+0, int mcount @+4, int hcount @+8
#define OFF_BP1    73728      // u16[8][8192]   (128 KB)
#define OFF_BP2    204800     // u16[64][1024]  (128 KB)
#define OFF_FB2    335872     // u64[64][1024]  (512 KB)
#define OFF_DIAG2  860160     // f32[1024]
#define OFF_A2     864256     // bf16[1024][256] (512 KB, swizzled by slot)
#define OFF_W1T    1388544    // bf16[256][512]  (256 KB, swizzled)
#define OFF_TB     1650688    // bf16[8192][256] (4 MB, swizzled)
#define OFF_VB     5844992    // bf16[8192][256] (4 MB, swizzled) -> end 10039296
#define OFF_TCB    10039296   // big path: bf16[8192][256] (4 MB)
#define OFF_VCB    14233600   // big path: bf16[8192][256] (4 MB) -> end 18427904
#define WS_BIG     18427904

__device__ __forceinline__ unsigned short f2bf(float x) {
    uint32_t u = __float_as_uint(x);
    return (unsigned short)((u + 0x7FFFu + ((u >> 16) & 1u)) >> 16);
}

__device__ __forceinline__ uint4 packbf8(float4 x, float4 y) {
    uint4 o;
    o.x = (uint32_t)f2bf(x.x) | ((uint32_t)f2bf(x.y) << 16);
    o.y = (uint32_t)f2bf(x.z) | ((uint32_t)f2bf(x.w) << 16);
    o.z = (uint32_t)f2bf(y.x) | ((uint32_t)f2bf(y.y) << 16);
    o.w = (uint32_t)f2bf(y.z) | ((uint32_t)f2bf(y.w) << 16);
    return o;
}

__device__ __forceinline__ unsigned fkey(float s) {
    unsigned u = __float_as_uint(s);
    return (u & 0x80000000u) ? ~u : (u | 0x80000000u);
}

__device__ __forceinline__ void cvt_block(const float* __restrict__ in,
                                          ushort_t* __restrict__ out,
                                          int bsub, int tid) {
    int i = bsub * 256 + tid;                   // 16B-chunk id
    int row = i >> 5, cw = i & 31, kb = cw >> 3, c = cw & 7;
    int csrc = c ^ (row & 7);
    const float4* src = (const float4*)(in + (size_t)row * DD + kb * 64 + csrc * 8);
    ((uint4*)out)[i] = packbf8(src[0], src[1]);
}

// ---------------- prep_uni: cvts (swizzled), diag, W1T, zero-init ----------------
__global__ __launch_bounds__(256) void prep_uni_kernel(const float* __restrict__ t,
                                                       const float* __restrict__ v,
                                                       const float* __restrict__ tcross,
                                                       const float* __restrict__ vcross,
                                                       const float* __restrict__ W1,
                                                       ushort_t* __restrict__ tb,
                                                       ushort_t* __restrict__ vb,
                                                       ushort_t* __restrict__ tcb,
                                                       ushort_t* __restrict__ vcb,
                                                       ushort_t* __restrict__ W1T,
                                                       float* __restrict__ diag,
                                                       uint32_t* __restrict__ zeroRegion) {
    const int b = blockIdx.x;
    const int tid = threadIdx.x;
    if (b < 2048) {
        cvt_block((b < 1024) ? t : v, (b < 1024) ? tb : vb, b & 1023, tid);
    } else if (b < 4096) {
        if (b == 2048 && tid < 3) zeroRegion[tid] = 0;   // acc + mcount + hcount
        int row = (b - 2048) * 4 + (tid >> 6);
        int lane = tid & 63;
        float4 a = *(const float4*)(t + (size_t)row * DD + lane * 4);
        float4 bb = *(const float4*)(v + (size_t)row * DD + lane * 4);
        float s = a.x * bb.x + a.y * bb.y + a.z * bb.z + a.w * bb.w;
        #pragma unroll
        for (int off = 32; off; off >>= 1) s += __shfl_down(s, off);
        if (lane == 0) diag[row] = s;
    } else if (b < 4128) {
        // W1T[n][k] = bf16(W1[k][n]), chunk-swizzled by n&7 within each 64-k block
        __shared__ float Ls[64][68];
        int tt = b - 4096;                          // 0..31
        int kb = tt >> 2, nb = tt & 3;
        int r = tid >> 2, q4 = tid & 3;
        #pragma unroll
        for (int j = 0; j < 4; j++) {
            float4 x = *(const float4*)(W1 + (size_t)(kb * 64 + r) * DD + nb * 64 + q4 * 16 + j * 4);
            *(float4*)&Ls[r][q4 * 16 + j * 4] = x;
        }
        __syncthreads();
        int rn = tid >> 2, cq = (tid & 3) * 2;
        #pragma unroll
        for (int cc = 0; cc < 2; cc++) {
            int c = cq + cc;
            int csrc = c ^ (rn & 7);
            float4 x, y;
            x.x = Ls[csrc * 8 + 0][rn]; x.y = Ls[csrc * 8 + 1][rn];
            x.z = Ls[csrc * 8 + 2][rn]; x.w = Ls[csrc * 8 + 3][rn];
            y.x = Ls[csrc * 8 + 4][rn]; y.y = Ls[csrc * 8 + 5][rn];
            y.z = Ls[csrc * 8 + 6][rn]; y.w = Ls[csrc * 8 + 7][rn];
            *(uint4*)&W1T[(size_t)(nb * 64 + rn) * 512 + kb * 64 + c * 8] = packbf8(x, y);
        }
    } else {
        // big path only: cross cvts
        int bb = b - 4128;
        cvt_block((bb < 1024) ? tcross : vcross, (bb < 1024) ? tcb : vcb, bb & 1023, tid);
    }
}

// ---------------- shared B-staging (proven R7) ----------------
__device__ __forceinline__ void stage_b(const ushort_t* __restrict__ VB, ushort_t* Bs,
                                        int colBase, int kc, int tid) {
    #pragma unroll
    for (int i = 0; i < 4; ++i) {
        int idx = i * 256 + tid;              // 0..1023
        int r = idx >> 3, c8 = idx & 7;       // source pre-swizzled -> linear copy
        __builtin_amdgcn_global_load_lds(
            (const __attribute__((address_space(1))) uint32_t*)(VB + (size_t)(colBase + r) * DD + kc + c8 * 8),
            (__attribute__((address_space(3))) uint32_t*)(Bs + idx * 8), 16, 0, 0);
    }
}

// ---------------- mine_p1: prefix cols [0,1024) (proven R9) ----------------
__global__ __launch_bounds__(256, 4) void mine_p1_kernel(const ushort_t* __restrict__ TB,
                                                         const ushort_t* __restrict__ VB,
                                                         const float* __restrict__ diag,
                                                         ushort_t* __restrict__ bp1) {
    __shared__ ushort_t Bs[2][128 * 64];       // 32 KB
    __shared__ float diag_s[128];

    const int tid = threadIdx.x;
    const int rowBase = blockIdx.x * 128;
    const int colBase = blockIdx.y * 128;      // y < 8
    const int lane = tid & 63;
    const int wave = tid >> 6;
    const int wr = wave >> 1, wc = wave & 1;
    const int lo = lane & 15, hi = lane >> 4;
    const int lx = lo & 7;

    if (tid < 128) diag_s[tid] = diag[rowBase + tid];

    f32x4 acc[4][4];
    #pragma unroll
    for (int m = 0; m < 4; m++)
        #pragma unroll
        for (int n = 0; n < 4; n++) acc[m][n] = (f32x4){0.f, 0.f, 0.f, 0.f};

    const ushort_t* Abase = TB + (size_t)(rowBase + wr * 64 + lo) * DD;

    stage_b(VB, Bs[0], colBase, 0, tid);
    __syncthreads();

    for (int kt = 0; kt < 4; ++kt) {
        const int buf = kt & 1;
        if (kt < 3)
            stage_b(VB, Bs[buf ^ 1], colBase, (kt + 1) * 64, tid);
        #pragma unroll
        for (int ksl = 0; ksl < 2; ksl++) {
            const int ch = ((((ksl << 2) | hi) ^ lx) << 3);
            bf16x8 a[4], b[4];
            #pragma unroll
            for (int m = 0; m < 4; m++)
                a[m] = *(const bf16x8*)(Abase + (size_t)m * 16 * DD + kt * 64 + ch);
            #pragma unroll
            for (int n = 0; n < 4; n++)
                b[n] = *(const bf16x8*)&Bs[buf][(wc * 64 + n * 16 + lo) * 64 + ch];
            #pragma unroll
            for (int m = 0; m < 4; m++)
                #pragma unroll
                for (int n = 0; n < 4; n++)
                    acc[m][n] = __builtin_amdgcn_mfma_f32_16x16x32_bf16(a[m], b[n], acc[m][n], 0, 0, 0);
        }
        __syncthreads();
    }

    #pragma unroll
    for (int m = 0; m < 4; m++) {
        #pragma unroll
        for (int q = 0; q < 4; q++) {
            const int rl = wr * 64 + m * 16 + hi * 4 + q;
            const int grow = rowBase + rl;
            const float c0 = diag_s[rl] - 0.35f;
            int bm = 0x7FFFFFFF;
            #pragma unroll
            for (int n = 0; n < 4; n++) {
                const float tt = acc[m][n][q] - c0;
                const int gcol = colBase + wc * 64 + n * 16 + lo;
                int cand = (fabsf(tt) < 0.15f && gcol != grow) ? gcol : 0x7FFFFFFF;
                bm = min(bm, cand);
            }
            #pragma unroll
            for (int off = 1; off < 16; off <<= 1) bm = min(bm, __shfl_xor(bm, off));
            if (lo == 0)
                bp1[blockIdx.y * NB + grow] = (ushort_t)min(bm, 0xFFFF);
        }
    }
}

// ---------------- combine_p1: prefix min; missing rows -> neg = -(slot+1) ----------------
__global__ __launch_bounds__(256) void combine_p1_kernel(const ushort_t* __restrict__ bp1,
                                                         int* __restrict__ neg,
                                                         int* __restrict__ mrows,
                                                         int* __restrict__ mcount) {
    int row = blockIdx.x * 256 + threadIdx.x;
    int bmin = 0xFFFF;
    #pragma unroll
    for (int g = 0; g < 8; g++) bmin = min(bmin, (int)bp1[g * NB + row]);
    if (bmin < 0xFFFF) {
        neg[row] = bmin;
    } else {
        int i = atomicAdd(mcount, 1);
        if (i < 1024) {
            mrows[i] = row;
            neg[row] = -(i + 1);                // resolved in head4
        } else {
            neg[row] = (row + 4096) & (NB - 1); // overflow placeholder (P ~ 0)
        }
    }
}

// ---------------- gather_p2: compact missing rows -> A2 (re-keyed swizzle), diag2 ----------------
__global__ __launch_bounds__(256) void gather_p2_kernel(const ushort_t* __restrict__ TB,
                                                        const float* __restrict__ diag,
                                                        const int* __restrict__ mrows,
                                                        const int* __restrict__ mcount,
                                                        ushort_t* __restrict__ A2,
                                                        float* __restrict__ diag2) {
    const int count = min(mcount[0], 1024);
    int idx = blockIdx.x * 256 + threadIdx.x;   // 16384 threads
    #pragma unroll
    for (int u = 0; u < 2; u++) {
        int t = idx * 2 + u;                    // chunk-copy id, 0..32767
        int s = t >> 5, c = t & 31;             // slot, 16B chunk
        int kb = c >> 3, cc = c & 7;
        uint4 val = {0, 0, 0, 0};
        if (s < count) {
            int r = mrows[s];
            int csrc = cc ^ ((s ^ r) & 7);      // re-key swizzle: tb keyed by r&7 -> A2 keyed by s&7
            val = *(const uint4*)(TB + (size_t)r * DD + kb * 64 + csrc * 8);
        }
        *(uint4*)(A2 + (size_t)s * DD + kb * 64 + cc * 8) = val;
    }
    if (idx < 1024) diag2[idx] = (idx < count) ? diag[mrows[idx]] : 0.f;
}

// ---------------- mine_p2: missing rows x all cols; band-min + argmax fallback ----------------
__global__ __launch_bounds__(256, 3) void mine_p2_kernel(const ushort_t* __restrict__ A2,
                                                         const ushort_t* __restrict__ VB,
                                                         const float* __restrict__ diag2,
                                                         const int* __restrict__ mrows,
                                                         const int* __restrict__ mcount,
                                                         ushort_t* __restrict__ bp2,
                                                         unsigned long long* __restrict__ fb2) {
    const int slotBase = blockIdx.x * 128;
    const int count = min(mcount[0], 1024);
    if (slotBase >= count) return;              // uniform early-out for inactive panels

    __shared__ ushort_t Bs[2][128 * 64];
    __shared__ float diag_s[128];
    __shared__ int rows_s[128];

    const int tid = threadIdx.x;
    const int colBase = blockIdx.y * 128;       // y < 64
    const int lane = tid & 63;
    const int wave = tid >> 6;
    const int wr = wave >> 1, wc = wave & 1;
    const int lo = lane & 15, hi = lane >> 4;
    const int lx = lo & 7;

    if (tid < 128) {
        diag_s[tid] = diag2[slotBase + tid];
        rows_s[tid] = mrows[slotBase + tid];    // garbage for pad slots; results discarded
    }

    f32x4 acc[4][4];
    #pragma unroll
    for (int m = 0; m < 4; m++)
        #pragma unroll
        for (int n = 0; n < 4; n++) acc[m][n] = (f32x4){0.f, 0.f, 0.f, 0.f};

    const ushort_t* Abase = A2 + (size_t)(slotBase + wr * 64 + lo) * DD;

    stage_b(VB, Bs[0], colBase, 0, tid);
    __syncthreads();

    for (int kt = 0; kt < 4; ++kt) {
        const int buf = kt & 1;
        if (kt < 3)
            stage_b(VB, Bs[buf ^ 1], colBase, (kt + 1) * 64, tid);
        #pragma unroll
        for (int ksl = 0; ksl < 2; ksl++) {
            const int ch = ((((ksl << 2) | hi) ^ lx) << 3);
            bf16x8 a[4], b[4];
            #pragma unroll
            for (int m = 0; m < 4; m++)
                a[m] = *(const bf16x8*)(Abase + (size_t)m * 16 * DD + kt * 64 + ch);
            #pragma unroll
            for (int n = 0; n < 4; n++)
                b[n] = *(const bf16x8*)&Bs[buf][(wc * 64 + n * 16 + lo) * 64 + ch];
            #pragma unroll
            for (int m = 0; m < 4; m++)
                #pragma unroll
                for (int n = 0; n < 4; n++)
                    acc[m][n] = __builtin_amdgcn_mfma_f32_16x16x32_bf16(a[m], b[n], acc[m][n], 0, 0, 0);
        }
        __syncthreads();
    }

    #pragma unroll
    for (int m = 0; m < 4; m++) {
        #pragma unroll
        for (int q = 0; q < 4; q++) {
            const int rl = wr * 64 + m * 16 + hi * 4 + q;
            const int actual = rows_s[rl];
            const float c0 = diag_s[rl] - 0.35f;
            int bm = 0x7FFFFFFF;
            unsigned long long pk = 0ULL;
            #pragma unroll
            for (int n = 0; n < 4; n++) {
                const float s = acc[m][n][q];
                const int gcol = colBase + wc * 64 + n * 16 + lo;
                if (gcol != actual) {
                    unsigned long long p = ((unsigned long long)fkey(s) << 32) | (unsigned)(NB - 1 - gcol);
                    pk = (p > pk) ? p : pk;
                    if (fabsf(s - c0) < 0.15f) bm = min(bm, gcol);
                }
            }
            #pragma unroll
            for (int off = 1; off < 16; off <<= 1) {
                unsigned long long po = __shfl_xor(pk, off);
                int bo = __shfl_xor(bm, off);
                pk = (po > pk) ? po : pk;
                bm = min(bm, bo);
            }
            if (lo == 0) {
                bp2[blockIdx.y * 1024 + slotBase + rl] = (ushort_t)min(bm, 0xFFFF);
                fb2[blockIdx.y * 1024 + slotBase + rl] = pk;
            }
        }
    }
}

// ---------------- prep_head (small path only): cvt tcross/vcross (swizzled) ----------------
__global__ __launch_bounds__(256) void prep_head_kernel(const float* __restrict__ tcross,
                                                        const float* __restrict__ vcross,
                                                        ushort_t* __restrict__ tb,
                                                        ushort_t* __restrict__ vb) {
    const int b = blockIdx.x;
    cvt_block((b < 1024) ? tcross : vcross, (b < 1024) ? tb : vb, b & 1023, threadIdx.x);
}

// ==================== head4: fused pos+neg, shared t-part, resolve + finalize ====================
__device__ __forceinline__ void stage_h4(const ushort_t* __restrict__ TCB,
                                         const ushort_t* __restrict__ VCB,
                                         const int* neg_l,
                                         const ushort_t* __restrict__ W1T,
                                         ushort_t* As, ushort_t* Bs,
                                         int rowBase, int kc, int tid) {
    if (kc < 256) {                               // A: 32 t-rows x 64 k
        int r = tid >> 3, c8 = tid & 7;
        __builtin_amdgcn_global_load_lds(
            (const __attribute__((address_space(1))) uint32_t*)(TCB + (size_t)(rowBase + r) * DD + kc + c8 * 8),
            (__attribute__((address_space(3))) uint32_t*)(As + tid * 8), 16, 0, 0);
    } else {                                      // A: 32 own v-rows + 32 neg v-rows x 64 k
        #pragma unroll
        for (int i = 0; i < 2; ++i) {
            int idx = i * 256 + tid;
            int r = idx >> 3, c8 = idx & 7;
            int rr = (r < 32) ? (rowBase + r) : neg_l[r - 32];
            int cs = c8 ^ ((r ^ rr) & 7);          // re-key rr&7 -> slot r&7
            __builtin_amdgcn_global_load_lds(
                (const __attribute__((address_space(1))) uint32_t*)(VCB + (size_t)rr * DD + (kc - 256) + cs * 8),
                (__attribute__((address_space(3))) uint32_t*)(As + idx * 8), 16, 0, 0);
        }
    }
    #pragma unroll
    for (int i = 0; i < 8; ++i) {                 // B: 256 cols x 64 k (W1T pre-swizzled)
        int idx = i * 256 + tid;
        int n = idx >> 3, c8 = idx & 7;
        __builtin_amdgcn_global_load_lds(
            (const __attribute__((address_space(1))) uint32_t*)(W1T + (size_t)n * 512 + kc + c8 * 8),
            (__attribute__((address_space(3))) uint32_t*)(Bs + idx * 8), 16, 0, 0);
    }
}

__global__ __launch_bounds__(256) void head4_kernel(const ushort_t* __restrict__ TCB,
                                                    const ushort_t* __restrict__ VCB,
                                                    const ushort_t* __restrict__ W1T,
                                                    const int* __restrict__ neg,
                                                    const ushort_t* __restrict__ bp2,
                                                    const unsigned long long* __restrict__ fb2,
                                                    const float* __restrict__ tcf,
                                                    const float* __restrict__ vcf,
                                                    const float* __restrict__ W1,
                                                    const float* __restrict__ b1,
                                                    const float* __restrict__ W2,
                                                    const float* __restrict__ b2,
                                                    float* __restrict__ acc_out,
                                                    int* __restrict__ hcount,
                                                    float* __restrict__ out) {
    __shared__ ushort_t As[2][64 * 64];           // 8 KB x2
    __shared__ ushort_t Bs[2][256 * 64];          // 32 KB x2
    __shared__ int neg_l[32];
    __shared__ float dotp_l[32], dotn_l[32];
    __shared__ float logit_p[32], logit_n[32];

    const int tid = threadIdx.x;
    const int rowBase = blockIdx.x * 32;
    const int lane = tid & 63;
    const int wcv = tid >> 6;                     // wave = col group (4 x 64 cols)
    const int lo = lane & 15, hi = lane >> 4;
    const int lx = lo & 7;

    // resolve missing neg rows (relocated combine_p2; <=1.4 rows/block expected)
    if (tid < 32) {
        int grow = rowBase + tid;
        int nv = neg[grow];
        if (nv < 0) {
            int s = -nv - 1;
            int bmin = 0xFFFF;
            unsigned long long pk = 0ULL;
            #pragma unroll
            for (int g = 0; g < 64; g++) {
                bmin = min(bmin, (int)bp2[g * 1024 + s]);
                unsigned long long f = fb2[g * 1024 + s];
                pk = (f > pk) ? f : pk;
            }
            nv = (bmin < 0xFFFF) ? bmin : (NB - 1 - (int)(unsigned)(pk & 0xFFFFFFFFull));
        }
        neg_l[tid] = nv;
        logit_p[tid] = 0.f;
        logit_n[tid] = 0.f;
    }
    __syncthreads();

    stage_h4(TCB, VCB, neg_l, W1T, As[0], Bs[0], rowBase, 0, tid);

    // dot features (fp32 exact), 8 threads/row, both pos & neg
    {
        int r = tid >> 3, e = tid & 7;
        int grow = rowBase + r;
        int vn = neg_l[r];
        const float4* tp = (const float4*)(tcf + (size_t)grow * DD + e * 32);
        const float4* vp = (const float4*)(vcf + (size_t)grow * DD + e * 32);
        const float4* vq = (const float4*)(vcf + (size_t)vn * DD + e * 32);
        float sp = 0.f, sn = 0.f;
        #pragma unroll
        for (int j = 0; j < 8; j++) {
            float4 a = tp[j], v = vp[j], w = vq[j];
            sp += a.x * v.x + a.y * v.y + a.z * v.z + a.w * v.w;
            sn += a.x * w.x + a.y * w.y + a.z * w.z + a.w * w.w;
        }
        #pragma unroll
        for (int off = 1; off < 8; off <<= 1) {
            sp += __shfl_xor(sp, off);
            sn += __shfl_xor(sn, off);
        }
        if (e == 0) { dotp_l[r] = sp; dotn_l[r] = sn; }
    }

    f32x4 acc_t[2][4], acc_p[2][4], acc_n[2][4];
    #pragma unroll
    for (int m = 0; m < 2; m++)
        #pragma unroll
        for (int n = 0; n < 4; n++) {
            acc_t[m][n] = (f32x4){0.f, 0.f, 0.f, 0.f};
            acc_p[m][n] = (f32x4){0.f, 0.f, 0.f, 0.f};
            acc_n[m][n] = (f32x4){0.f, 0.f, 0.f, 0.f};
        }

    __syncthreads();                              // drains stage(0)

    for (int kt = 0; kt < 8; ++kt) {
        const int buf = kt & 1;
        if (kt < 7)
            stage_h4(TCB, VCB, neg_l, W1T, As[buf ^ 1], Bs[buf ^ 1], rowBase, (kt + 1) * 64, tid);
        #pragma unroll
        for (int ksl = 0; ksl < 2; ksl++) {
            const int ch = ((((ksl << 2) | hi) ^ lx) << 3);
            bf16x8 b[4];
            #pragma unroll
            for (int n = 0; n < 4; n++)
                b[n] = *(const bf16x8*)&Bs[buf][(wcv * 64 + n * 16 + lo) * 64 + ch];
            if (kt < 4) {                         // t-phase -> acc_t
                bf16x8 a[2];
                #pragma unroll
                for (int m = 0; m < 2; m++)
                    a[m] = *(const bf16x8*)&As[buf][(m * 16 + lo) * 64 + ch];
                #pragma unroll
                for (int m = 0; m < 2; m++)
                    #pragma unroll
                    for (int n = 0; n < 4; n++)
                        acc_t[m][n] = __builtin_amdgcn_mfma_f32_16x16x32_bf16(a[m], b[n], acc_t[m][n], 0, 0, 0);
            } else {                              // v-phase -> acc_p (rows 0-31) + acc_n (rows 32-63)
                bf16x8 ap[2], an[2];
                #pragma unroll
                for (int m = 0; m < 2; m++) {
                    ap[m] = *(const bf16x8*)&As[buf][(m * 16 + lo) * 64 + ch];
                    an[m] = *(const bf16x8*)&As[buf][(32 + m * 16 + lo) * 64 + ch];
                }
                #pragma unroll
                for (int m = 0; m < 2; m++)
                    #pragma unroll
                    for (int n = 0; n < 4; n++) {
                        acc_p[m][n] = __builtin_amdgcn_mfma_f32_16x16x32_bf16(ap[m], b[n], acc_p[m][n], 0, 0, 0);
                        acc_n[m][n] = __builtin_amdgcn_mfma_f32_16x16x32_bf16(an[m], b[n], acc_n[m][n], 0, 0, 0);
                    }
            }
        }
        __syncthreads();
    }

    // epilogue: h = relu(acc_t + acc_v + b1 + dot*W1[512]); logit = h @ W2
    float b1v[4], w5v[4], w2v[4];
    #pragma unroll
    for (int n = 0; n < 4; n++) {
        int cl = wcv * 64 + n * 16 + lo;
        b1v[n] = b1[cl];
        w5v[n] = W1[(size_t)512 * DD + cl];
        w2v[n] = W2[cl];
    }
    #pragma unroll
    for (int m = 0; m < 2; m++) {
        #pragma unroll
        for (int q = 0; q < 4; q++) {
            const int rl = m * 16 + hi * 4 + q;
            const float dtp = dotp_l[rl], dtn = dotn_l[rl];
            float xp = 0.f, xn = 0.f;
            #pragma unroll
            for (int n = 0; n < 4; n++) {
                float base = acc_t[m][n][q] + b1v[n];
                float hp = base + acc_p[m][n][q] + dtp * w5v[n];
                float hn = base + acc_n[m][n][q] + dtn * w5v[n];
                xp += fmaxf(hp, 0.f) * w2v[n];
                xn += fmaxf(hn, 0.f) * w2v[n];
            }
            #pragma unroll
            for (int off = 1; off < 16; off <<= 1) {
                xp += __shfl_xor(xp, off);
                xn += __shfl_xor(xn, off);
            }
            if (lo == 0) {
                atomicAdd(&logit_p[rl], xp);
                atomicAdd(&logit_n[rl], xn);
            }
        }
    }
    __syncthreads();

    if (tid < 32) {
        float bb = b2[0];
        float xp = logit_p[tid] + bb;
        float xn = logit_n[tid] + bb;
        // pos: -log(sigmoid(xp)+eps); neg: -log(1-sigmoid(xn)+eps) = -log(sigmoid(-xn)+eps)
        float term = -logf(1.f / (1.f + expf(-xp)) + 1e-8f)
                     -logf(1.f / (1.f + expf(xn)) + 1e-8f);
        #pragma unroll
        for (int off = 16; off; off >>= 1) term += __shfl_down(term, off);
        if (tid == 0) {
            atomicAdd(acc_out, term);
            __threadfence();
            int done = atomicAdd(hcount, 1);
            if (done == (int)gridDim.x - 1) {
                float total = atomicAdd(acc_out, 0.f);   // all adds fenced-in
                out[0] = total * (1.0f / (2.0f * (float)NB));
            }
        }
    }
}

// ==================== launch ====================
extern "C" void kernel_launch(void* const* d_in, const int* in_sizes, int n_in,
                              void* d_out, int out_size, void* d_ws, size_t ws_size,
                              hipStream_t stream) {
    const float* vcross = (const float*)d_in[0];
    const float* tcross = (const float*)d_in[1];
    const float* vuni   = (const float*)d_in[2];
    const float* tuni   = (const float*)d_in[3];
    const float* W1     = (const float*)d_in[4];
    const float* b1     = (const float*)d_in[5];
    const float* W2     = (const float*)d_in[6];
    const float* b2     = (const float*)d_in[7];

    char* ws = (char*)d_ws;
    float* diag   = (float*)(ws + OFF_DIAG);
    int* neg      = (int*)(ws + OFF_NEG);
    int* mrows    = (int*)(ws + OFF_MROWS);
    float* acc    = (float*)(ws + OFF_ACC);
    int* mcount   = (int*)(ws + OFF_ACC + 4);
    int* hcount   = (int*)(ws + OFF_ACC + 8);
    ushort_t* bp1 = (ushort_t*)(ws + OFF_BP1);
    ushort_t* bp2 = (ushort_t*)(ws + OFF_BP2);
    unsigned long long* fb2 = (unsigned long long*)(ws + OFF_FB2);
    float* diag2  = (float*)(ws + OFF_DIAG2);
    ushort_t* A2  = (ushort_t*)(ws + OFF_A2);
    ushort_t* w1t = (ushort_t*)(ws + OFF_W1T);
    ushort_t* tb  = (ushort_t*)(ws + OFF_TB);
    ushort_t* vb  = (ushort_t*)(ws + OFF_VB);

    const int big = (ws_size >= (size_t)WS_BIG);
    ushort_t* tcb = big ? (ushort_t*)(ws + OFF_TCB) : tb;
    ushort_t* vcb = big ? (ushort_t*)(ws + OFF_VCB) : vb;

    prep_uni_kernel<<<big ? 6176 : 4128, 256, 0, stream>>>(
        tuni, vuni, tcross, vcross, W1, tb, vb, tcb, vcb, w1t, diag,
        (uint32_t*)(ws + OFF_ACC));
    mine_p1_kernel<<<dim3(64, 8), 256, 0, stream>>>(tb, vb, diag, bp1);
    combine_p1_kernel<<<NB / 256, 256, 0, stream>>>(bp1, neg, mrows, mcount);
    gather_p2_kernel<<<64, 256, 0, stream>>>(tb, diag, mrows, mcount, A2, diag2);
    mine_p2_kernel<<<dim3(8, 64), 256, 0, stream>>>(A2, vb, diag2, mrows, mcount, bp2, fb2);
    if (!big)
        prep_head_kernel<<<2048, 256, 0, stream>>>(tcross, vcross, tb, vb);
    head4_kernel<<<NB / 32, 256, 0, stream>>>(tcb, vcb, w1t, neg, bp2, fb2,
                                              tcross, vcross, W1, b1, W2, b2,
                                              acc, hcount, (float*)d_out);
}

// Round 14
// 72.750 us; speedup vs baseline: 1.1438x; 1.0412x over previous
//
#include <hip/hip_runtime.h>
#include <stdint.h>

#define NB 8192
#define DD 256

typedef unsigned short ushort_t;
typedef __attribute__((ext_vector_type(8))) short bf16x8;
typedef __attribute__((ext_vector_type(4))) float f32x4;

// ==================== workspace layout ====================
// small path (<= proven 10039296); big path adds cross buffers (gated on ws_size)
#define OFF_DIAG   0          // f32[8192]
#define OFF_NEG    32768      // int[8192]
#define OFF_MROWS  65536      // int[1024]
#define OFF_ACC    69632      // f32 acc @+0, int mcount @+4, int hcount @+8
#define OFF_BP1    73728      // u16[8][8192]   (128 KB)
#define OFF_BP2    204800     // u16[64][1024]  (128 KB)
#define OFF_FB2    335872     // u64[64][1024]  (512 KB)
#define OFF_DIAG2  860160     // f32[1024]
#define OFF_A2     864256     // bf16[1024][256] (512 KB, swizzled by slot)
#define OFF_W1T    1388544    // bf16[256][512]  (256 KB, swizzled)
#define OFF_TB     1650688    // bf16[8192][256] (4 MB, swizzled)
#define OFF_VB     5844992    // bf16[8192][256] (4 MB, swizzled) -> end 10039296
#define OFF_TCB    10039296   // big path: bf16[8192][256] (4 MB)
#define OFF_VCB    14233600   // big path: bf16[8192][256] (4 MB) -> end 18427904
#define WS_BIG     18427904

__device__ __forceinline__ unsigned short f2bf(float x) {
    uint32_t u = __float_as_uint(x);
    return (unsigned short)((u + 0x7FFFu + ((u >> 16) & 1u)) >> 16);
}

__device__ __forceinline__ uint4 packbf8(float4 x, float4 y) {
    uint4 o;
    o.x = (uint32_t)f2bf(x.x) | ((uint32_t)f2bf(x.y) << 16);
    o.y = (uint32_t)f2bf(x.z) | ((uint32_t)f2bf(x.w) << 16);
    o.z = (uint32_t)f2bf(y.x) | ((uint32_t)f2bf(y.y) << 16);
    o.w = (uint32_t)f2bf(y.z) | ((uint32_t)f2bf(y.w) << 16);
    return o;
}

__device__ __forceinline__ unsigned fkey(float s) {
    unsigned u = __float_as_uint(s);
    return (u & 0x80000000u) ? ~u : (u | 0x80000000u);
}

__device__ __forceinline__ void cvt_block(const float* __restrict__ in,
                                          ushort_t* __restrict__ out,
                                          int bsub, int tid) {
    int i = bsub * 256 + tid;                   // 16B-chunk id
    int row = i >> 5, cw = i & 31, kb = cw >> 3, c = cw & 7;
    int csrc = c ^ (row & 7);
    const float4* src = (const float4*)(in + (size_t)row * DD + kb * 64 + csrc * 8);
    ((uint4*)out)[i] = packbf8(src[0], src[1]);
}

// ---------------- prep_uni: fused cvt(t,v)+diag, W1T, [big: cross cvts], zero-init ----------------
__global__ __launch_bounds__(256) void prep_uni_kernel(const float* __restrict__ t,
                                                       const float* __restrict__ v,
                                                       const float* __restrict__ tcross,
                                                       const float* __restrict__ vcross,
                                                       const float* __restrict__ W1,
                                                       ushort_t* __restrict__ tb,
                                                       ushort_t* __restrict__ vb,
                                                       ushort_t* __restrict__ tcb,
                                                       ushort_t* __restrict__ vcb,
                                                       ushort_t* __restrict__ W1T,
                                                       float* __restrict__ diag,
                                                       uint32_t* __restrict__ zeroRegion) {
    const int b = blockIdx.x;
    const int tid = threadIdx.x;
    if (b < 1024) {
        // fused: cvt t & v rows 8b..8b+7 (swizzled) + diag partials
        if (b == 0 && tid < 3) zeroRegion[tid] = 0;     // acc + mcount + hcount
        int r = b * 8 + (tid >> 5);
        int cw = tid & 31, kb = cw >> 3, c = cw & 7;
        int csrc = c ^ (r & 7);
        const float4* ts = (const float4*)(t + (size_t)r * DD + kb * 64 + csrc * 8);
        const float4* vs = (const float4*)(v + (size_t)r * DD + kb * 64 + csrc * 8);
        float4 t0 = ts[0], t1 = ts[1];
        float4 v0 = vs[0], v1 = vs[1];
        ((uint4*)tb)[(size_t)r * 32 + cw] = packbf8(t0, t1);
        ((uint4*)vb)[(size_t)r * 32 + cw] = packbf8(v0, v1);
        float s = t0.x * v0.x + t0.y * v0.y + t0.z * v0.z + t0.w * v0.w
                + t1.x * v1.x + t1.y * v1.y + t1.z * v1.z + t1.w * v1.w;
        #pragma unroll
        for (int off = 1; off < 32; off <<= 1) s += __shfl_xor(s, off);
        if ((tid & 31) == 0) diag[r] = s;
    } else if (b < 1056) {
        // W1T[n][k] = bf16(W1[k][n]), chunk-swizzled by n&7 within each 64-k block
        __shared__ float Ls[64][68];
        int tt = b - 1024;                          // 0..31
        int kb = tt >> 2, nb = tt & 3;
        int r = tid >> 2, q4 = tid & 3;
        #pragma unroll
        for (int j = 0; j < 4; j++) {
            float4 x = *(const float4*)(W1 + (size_t)(kb * 64 + r) * DD + nb * 64 + q4 * 16 + j * 4);
            *(float4*)&Ls[r][q4 * 16 + j * 4] = x;
        }
        __syncthreads();
        int rn = tid >> 2, cq = (tid & 3) * 2;
        #pragma unroll
        for (int cc = 0; cc < 2; cc++) {
            int c = cq + cc;
            int csrc = c ^ (rn & 7);
            float4 x, y;
            x.x = Ls[csrc * 8 + 0][rn]; x.y = Ls[csrc * 8 + 1][rn];
            x.z = Ls[csrc * 8 + 2][rn]; x.w = Ls[csrc * 8 + 3][rn];
            y.x = Ls[csrc * 8 + 4][rn]; y.y = Ls[csrc * 8 + 5][rn];
            y.z = Ls[csrc * 8 + 6][rn]; y.w = Ls[csrc * 8 + 7][rn];
            *(uint4*)&W1T[(size_t)(nb * 64 + rn) * 512 + kb * 64 + c * 8] = packbf8(x, y);
        }
    } else {
        // big path only: cross cvts
        int bb = b - 1056;
        cvt_block((bb < 1024) ? tcross : vcross, (bb < 1024) ? tcb : vcb, bb & 1023, tid);
    }
}

// ---------------- shared B-staging (proven R7) ----------------
__device__ __forceinline__ void stage_b(const ushort_t* __restrict__ VB, ushort_t* Bs,
                                        int colBase, int kc, int tid) {
    #pragma unroll
    for (int i = 0; i < 4; ++i) {
        int idx = i * 256 + tid;              // 0..1023
        int r = idx >> 3, c8 = idx & 7;       // source pre-swizzled -> linear copy
        __builtin_amdgcn_global_load_lds(
            (const __attribute__((address_space(1))) uint32_t*)(VB + (size_t)(colBase + r) * DD + kc + c8 * 8),
            (__attribute__((address_space(3))) uint32_t*)(Bs + idx * 8), 16, 0, 0);
    }
}

// ---------------- mine_p1: prefix cols [0,1024) (proven R9) ----------------
__global__ __launch_bounds__(256, 4) void mine_p1_kernel(const ushort_t* __restrict__ TB,
                                                         const ushort_t* __restrict__ VB,
                                                         const float* __restrict__ diag,
                                                         ushort_t* __restrict__ bp1) {
    __shared__ ushort_t Bs[2][128 * 64];       // 32 KB
    __shared__ float diag_s[128];

    const int tid = threadIdx.x;
    const int rowBase = blockIdx.x * 128;
    const int colBase = blockIdx.y * 128;      // y < 8
    const int lane = tid & 63;
    const int wave = tid >> 6;
    const int wr = wave >> 1, wc = wave & 1;
    const int lo = lane & 15, hi = lane >> 4;
    const int lx = lo & 7;

    if (tid < 128) diag_s[tid] = diag[rowBase + tid];

    f32x4 acc[4][4];
    #pragma unroll
    for (int m = 0; m < 4; m++)
        #pragma unroll
        for (int n = 0; n < 4; n++) acc[m][n] = (f32x4){0.f, 0.f, 0.f, 0.f};

    const ushort_t* Abase = TB + (size_t)(rowBase + wr * 64 + lo) * DD;

    stage_b(VB, Bs[0], colBase, 0, tid);
    __syncthreads();

    for (int kt = 0; kt < 4; ++kt) {
        const int buf = kt & 1;
        if (kt < 3)
            stage_b(VB, Bs[buf ^ 1], colBase, (kt + 1) * 64, tid);
        #pragma unroll
        for (int ksl = 0; ksl < 2; ksl++) {
            const int ch = ((((ksl << 2) | hi) ^ lx) << 3);
            bf16x8 a[4], b[4];
            #pragma unroll
            for (int m = 0; m < 4; m++)
                a[m] = *(const bf16x8*)(Abase + (size_t)m * 16 * DD + kt * 64 + ch);
            #pragma unroll
            for (int n = 0; n < 4; n++)
                b[n] = *(const bf16x8*)&Bs[buf][(wc * 64 + n * 16 + lo) * 64 + ch];
            #pragma unroll
            for (int m = 0; m < 4; m++)
                #pragma unroll
                for (int n = 0; n < 4; n++)
                    acc[m][n] = __builtin_amdgcn_mfma_f32_16x16x32_bf16(a[m], b[n], acc[m][n], 0, 0, 0);
        }
        __syncthreads();
    }

    #pragma unroll
    for (int m = 0; m < 4; m++) {
        #pragma unroll
        for (int q = 0; q < 4; q++) {
            const int rl = wr * 64 + m * 16 + hi * 4 + q;
            const int grow = rowBase + rl;
            const float c0 = diag_s[rl] - 0.35f;
            int bm = 0x7FFFFFFF;
            #pragma unroll
            for (int n = 0; n < 4; n++) {
                const float tt = acc[m][n][q] - c0;
                const int gcol = colBase + wc * 64 + n * 16 + lo;
                int cand = (fabsf(tt) < 0.15f && gcol != grow) ? gcol : 0x7FFFFFFF;
                bm = min(bm, cand);
            }
            #pragma unroll
            for (int off = 1; off < 16; off <<= 1) bm = min(bm, __shfl_xor(bm, off));
            if (lo == 0)
                bp1[blockIdx.y * NB + grow] = (ushort_t)min(bm, 0xFFFF);
        }
    }
}

// ---------------- combine_p1 (+absorbed gather): prefix min; missing rows -> slot + panel copy ----------------
__global__ __launch_bounds__(256) void combine_p1_kernel(const ushort_t* __restrict__ bp1,
                                                         const float* __restrict__ diag,
                                                         const ushort_t* __restrict__ TB,
                                                         int* __restrict__ neg,
                                                         int* __restrict__ mrows,
                                                         int* __restrict__ mcount,
                                                         ushort_t* __restrict__ A2,
                                                         float* __restrict__ diag2) {
    int row = blockIdx.x * 256 + threadIdx.x;
    int bmin = 0xFFFF;
    #pragma unroll
    for (int g = 0; g < 8; g++) bmin = min(bmin, (int)bp1[g * NB + row]);
    if (bmin < 0xFFFF) {
        neg[row] = bmin;
    } else {
        int i = atomicAdd(mcount, 1);
        if (i < 1024) {
            mrows[i] = row;
            neg[row] = -(i + 1);                // resolved in head4
            diag2[i] = diag[row];
            // copy row panel tb[row] -> A2[i], re-key swizzle (row&7 -> i&7)
            const uint4* src = (const uint4*)(TB + (size_t)row * DD);
            uint4* dst = (uint4*)(A2 + (size_t)i * DD);
            int kx = (i ^ row) & 7;
            #pragma unroll
            for (int cw = 0; cw < 32; cw++) {
                int kb = cw >> 3, c = cw & 7;
                dst[kb * 8 + c] = src[kb * 8 + (c ^ kx)];
            }
        } else {
            neg[row] = (row + 4096) & (NB - 1); // overflow placeholder (P ~ 0)
        }
    }
}

// ---------------- mine_p2: missing rows x all cols; band-min + argmax fallback ----------------
__global__ __launch_bounds__(256, 3) void mine_p2_kernel(const ushort_t* __restrict__ A2,
                                                         const ushort_t* __restrict__ VB,
                                                         const float* __restrict__ diag2,
                                                         const int* __restrict__ mrows,
                                                         const int* __restrict__ mcount,
                                                         ushort_t* __restrict__ bp2,
                                                         unsigned long long* __restrict__ fb2) {
    const int slotBase = blockIdx.x * 128;
    const int count = min(mcount[0], 1024);
    if (slotBase >= count) return;              // uniform early-out for inactive panels

    __shared__ ushort_t Bs[2][128 * 64];
    __shared__ float diag_s[128];
    __shared__ int rows_s[128];

    const int tid = threadIdx.x;
    const int colBase = blockIdx.y * 128;       // y < 64
    const int lane = tid & 63;
    const int wave = tid >> 6;
    const int wr = wave >> 1, wc = wave & 1;
    const int lo = lane & 15, hi = lane >> 4;
    const int lx = lo & 7;

    if (tid < 128) {
        diag_s[tid] = diag2[slotBase + tid];
        rows_s[tid] = mrows[slotBase + tid];    // garbage for pad slots; results discarded
    }

    f32x4 acc[4][4];
    #pragma unroll
    for (int m = 0; m < 4; m++)
        #pragma unroll
        for (int n = 0; n < 4; n++) acc[m][n] = (f32x4){0.f, 0.f, 0.f, 0.f};

    const ushort_t* Abase = A2 + (size_t)(slotBase + wr * 64 + lo) * DD;

    stage_b(VB, Bs[0], colBase, 0, tid);
    __syncthreads();

    for (int kt = 0; kt < 4; ++kt) {
        const int buf = kt & 1;
        if (kt < 3)
            stage_b(VB, Bs[buf ^ 1], colBase, (kt + 1) * 64, tid);
        #pragma unroll
        for (int ksl = 0; ksl < 2; ksl++) {
            const int ch = ((((ksl << 2) | hi) ^ lx) << 3);
            bf16x8 a[4], b[4];
            #pragma unroll
            for (int m = 0; m < 4; m++)
                a[m] = *(const bf16x8*)(Abase + (size_t)m * 16 * DD + kt * 64 + ch);
            #pragma unroll
            for (int n = 0; n < 4; n++)
                b[n] = *(const bf16x8*)&Bs[buf][(wc * 64 + n * 16 + lo) * 64 + ch];
            #pragma unroll
            for (int m = 0; m < 4; m++)
                #pragma unroll
                for (int n = 0; n < 4; n++)
                    acc[m][n] = __builtin_amdgcn_mfma_f32_16x16x32_bf16(a[m], b[n], acc[m][n], 0, 0, 0);
        }
        __syncthreads();
    }

    #pragma unroll
    for (int m = 0; m < 4; m++) {
        #pragma unroll
        for (int q = 0; q < 4; q++) {
            const int rl = wr * 64 + m * 16 + hi * 4 + q;
            const int actual = rows_s[rl];
            const float c0 = diag_s[rl] - 0.35f;
            int bm = 0x7FFFFFFF;
            unsigned long long pk = 0ULL;
            #pragma unroll
            for (int n = 0; n < 4; n++) {
                const float s = acc[m][n][q];
                const int gcol = colBase + wc * 64 + n * 16 + lo;
                if (gcol != actual) {
                    unsigned long long p = ((unsigned long long)fkey(s) << 32) | (unsigned)(NB - 1 - gcol);
                    pk = (p > pk) ? p : pk;
                    if (fabsf(s - c0) < 0.15f) bm = min(bm, gcol);
                }
            }
            #pragma unroll
            for (int off = 1; off < 16; off <<= 1) {
                unsigned long long po = __shfl_xor(pk, off);
                int bo = __shfl_xor(bm, off);
                pk = (po > pk) ? po : pk;
                bm = min(bm, bo);
            }
            if (lo == 0) {
                bp2[blockIdx.y * 1024 + slotBase + rl] = (ushort_t)min(bm, 0xFFFF);
                fb2[blockIdx.y * 1024 + slotBase + rl] = pk;
            }
        }
    }
}

// ---------------- prep_head (small path only): cvt tcross/vcross (swizzled) ----------------
__global__ __launch_bounds__(256) void prep_head_kernel(const float* __restrict__ tcross,
                                                        const float* __restrict__ vcross,
                                                        ushort_t* __restrict__ tb,
                                                        ushort_t* __restrict__ vb) {
    const int b = blockIdx.x;
    cvt_block((b < 1024) ? tcross : vcross, (b < 1024) ? tb : vb, b & 1023, threadIdx.x);
}

// ==================== head4: fused pos+neg, shared t-part, resolve + finalize (proven R13) ====================
__device__ __forceinline__ void stage_h4(const ushort_t* __restrict__ TCB,
                                         const ushort_t* __restrict__ VCB,
                                         const int* neg_l,
                                         const ushort_t* __restrict__ W1T,
                                         ushort_t* As, ushort_t* Bs,
                                         int rowBase, int kc, int tid) {
    if (kc < 256) {                               // A: 32 t-rows x 64 k
        int r = tid >> 3, c8 = tid & 7;
        __builtin_amdgcn_global_load_lds(
            (const __attribute__((address_space(1))) uint32_t*)(TCB + (size_t)(rowBase + r) * DD + kc + c8 * 8),
            (__attribute__((address_space(3))) uint32_t*)(As + tid * 8), 16, 0, 0);
    } else {                                      // A: 32 own v-rows + 32 neg v-rows x 64 k
        #pragma unroll
        for (int i = 0; i < 2; ++i) {
            int idx = i * 256 + tid;
            int r = idx >> 3, c8 = idx & 7;
            int rr = (r < 32) ? (rowBase + r) : neg_l[r - 32];
            int cs = c8 ^ ((r ^ rr) & 7);          // re-key rr&7 -> slot r&7
            __builtin_amdgcn_global_load_lds(
                (const __attribute__((address_space(1))) uint32_t*)(VCB + (size_t)rr * DD + (kc - 256) + cs * 8),
                (__attribute__((address_space(3))) uint32_t*)(As + idx * 8), 16, 0, 0);
        }
    }
    #pragma unroll
    for (int i = 0; i < 8; ++i) {                 // B: 256 cols x 64 k (W1T pre-swizzled)
        int idx = i * 256 + tid;
        int n = idx >> 3, c8 = idx & 7;
        __builtin_amdgcn_global_load_lds(
            (const __attribute__((address_space(1))) uint32_t*)(W1T + (size_t)n * 512 + kc + c8 * 8),
            (__attribute__((address_space(3))) uint32_t*)(Bs + idx * 8), 16, 0, 0);
    }
}

__global__ __launch_bounds__(256) void head4_kernel(const ushort_t* __restrict__ TCB,
                                                    const ushort_t* __restrict__ VCB,
                                                    const ushort_t* __restrict__ W1T,
                                                    const int* __restrict__ neg,
                                                    const ushort_t* __restrict__ bp2,
                                                    const unsigned long long* __restrict__ fb2,
                                                    const float* __restrict__ tcf,
                                                    const float* __restrict__ vcf,
                                                    const float* __restrict__ W1,
                                                    const float* __restrict__ b1,
                                                    const float* __restrict__ W2,
                                                    const float* __restrict__ b2,
                                                    float* __restrict__ acc_out,
                                                    int* __restrict__ hcount,
                                                    float* __restrict__ out) {
    __shared__ ushort_t As[2][64 * 64];           // 8 KB x2
    __shared__ ushort_t Bs[2][256 * 64];          // 32 KB x2
    __shared__ int neg_l[32];
    __shared__ float dotp_l[32], dotn_l[32];
    __shared__ float logit_p[32], logit_n[32];

    const int tid = threadIdx.x;
    const int rowBase = blockIdx.x * 32;
    const int lane = tid & 63;
    const int wcv = tid >> 6;                     // wave = col group (4 x 64 cols)
    const int lo = lane & 15, hi = lane >> 4;
    const int lx = lo & 7;

    // resolve missing neg rows (relocated combine_p2; <=1.4 rows/block expected)
    if (tid < 32) {
        int grow = rowBase + tid;
        int nv = neg[grow];
        if (nv < 0) {
            int s = -nv - 1;
            int bmin = 0xFFFF;
            unsigned long long pk = 0ULL;
            #pragma unroll
            for (int g = 0; g < 64; g++) {
                bmin = min(bmin, (int)bp2[g * 1024 + s]);
                unsigned long long f = fb2[g * 1024 + s];
                pk = (f > pk) ? f : pk;
            }
            nv = (bmin < 0xFFFF) ? bmin : (NB - 1 - (int)(unsigned)(pk & 0xFFFFFFFFull));
        }
        neg_l[tid] = nv;
        logit_p[tid] = 0.f;
        logit_n[tid] = 0.f;
    }
    __syncthreads();

    stage_h4(TCB, VCB, neg_l, W1T, As[0], Bs[0], rowBase, 0, tid);

    // dot features (fp32 exact), 8 threads/row, both pos & neg
    {
        int r = tid >> 3, e = tid & 7;
        int grow = rowBase + r;
        int vn = neg_l[r];
        const float4* tp = (const float4*)(tcf + (size_t)grow * DD + e * 32);
        const float4* vp = (const float4*)(vcf + (size_t)grow * DD + e * 32);
        const float4* vq = (const float4*)(vcf + (size_t)vn * DD + e * 32);
        float sp = 0.f, sn = 0.f;
        #pragma unroll
        for (int j = 0; j < 8; j++) {
            float4 a = tp[j], v = vp[j], w = vq[j];
            sp += a.x * v.x + a.y * v.y + a.z * v.z + a.w * v.w;
            sn += a.x * w.x + a.y * w.y + a.z * w.z + a.w * w.w;
        }
        #pragma unroll
        for (int off = 1; off < 8; off <<= 1) {
            sp += __shfl_xor(sp, off);
            sn += __shfl_xor(sn, off);
        }
        if (e == 0) { dotp_l[r] = sp; dotn_l[r] = sn; }
    }

    f32x4 acc_t[2][4], acc_p[2][4], acc_n[2][4];
    #pragma unroll
    for (int m = 0; m < 2; m++)
        #pragma unroll
        for (int n = 0; n < 4; n++) {
            acc_t[m][n] = (f32x4){0.f, 0.f, 0.f, 0.f};
            acc_p[m][n] = (f32x4){0.f, 0.f, 0.f, 0.f};
            acc_n[m][n] = (f32x4){0.f, 0.f, 0.f, 0.f};
        }

    __syncthreads();                              // drains stage(0)

    for (int kt = 0; kt < 8; ++kt) {
        const int buf = kt & 1;
        if (kt < 7)
            stage_h4(TCB, VCB, neg_l, W1T, As[buf ^ 1], Bs[buf ^ 1], rowBase, (kt + 1) * 64, tid);
        #pragma unroll
        for (int ksl = 0; ksl < 2; ksl++) {
            const int ch = ((((ksl << 2) | hi) ^ lx) << 3);
            bf16x8 b[4];
            #pragma unroll
            for (int n = 0; n < 4; n++)
                b[n] = *(const bf16x8*)&Bs[buf][(wcv * 64 + n * 16 + lo) * 64 + ch];
            if (kt < 4) {                         // t-phase -> acc_t
                bf16x8 a[2];
                #pragma unroll
                for (int m = 0; m < 2; m++)
                    a[m] = *(const bf16x8*)&As[buf][(m * 16 + lo) * 64 + ch];
                #pragma unroll
                for (int m = 0; m < 2; m++)
                    #pragma unroll
                    for (int n = 0; n < 4; n++)
                        acc_t[m][n] = __builtin_amdgcn_mfma_f32_16x16x32_bf16(a[m], b[n], acc_t[m][n], 0, 0, 0);
            } else {                              // v-phase -> acc_p (rows 0-31) + acc_n (rows 32-63)
                bf16x8 ap[2], an[2];
                #pragma unroll
                for (int m = 0; m < 2; m++) {
                    ap[m] = *(const bf16x8*)&As[buf][(m * 16 + lo) * 64 + ch];
                    an[m] = *(const bf16x8*)&As[buf][(32 + m * 16 + lo) * 64 + ch];
                }
                #pragma unroll
                for (int m = 0; m < 2; m++)
                    #pragma unroll
                    for (int n = 0; n < 4; n++) {
                        acc_p[m][n] = __builtin_amdgcn_mfma_f32_16x16x32_bf16(ap[m], b[n], acc_p[m][n], 0, 0, 0);
                        acc_n[m][n] = __builtin_amdgcn_mfma_f32_16x16x32_bf16(an[m], b[n], acc_n[m][n], 0, 0, 0);
                    }
            }
        }
        __syncthreads();
    }

    // epilogue: h = relu(acc_t + acc_v + b1 + dot*W1[512]); logit = h @ W2
    float b1v[4], w5v[4], w2v[4];
    #pragma unroll
    for (int n = 0; n < 4; n++) {
        int cl = wcv * 64 + n * 16 + lo;
        b1v[n] = b1[cl];
        w5v[n] = W1[(size_t)512 * DD + cl];
        w2v[n] = W2[cl];
    }
    #pragma unroll
    for (int m = 0; m < 2; m++) {
        #pragma unroll
        for (int q = 0; q < 4; q++) {
            const int rl = m * 16 + hi * 4 + q;
            const float dtp = dotp_l[rl], dtn = dotn_l[rl];
            float xp = 0.f, xn = 0.f;
            #pragma unroll
            for (int n = 0; n < 4; n++) {
                float base = acc_t[m][n][q] + b1v[n];
                float hp = base + acc_p[m][n][q] + dtp * w5v[n];
                float hn = base + acc_n[m][n][q] + dtn * w5v[n];
                xp += fmaxf(hp, 0.f) * w2v[n];
                xn += fmaxf(hn, 0.f) * w2v[n];
            }
            #pragma unroll
            for (int off = 1; off < 16; off <<= 1) {
                xp += __shfl_xor(xp, off);
                xn += __shfl_xor(xn, off);
            }
            if (lo == 0) {
                atomicAdd(&logit_p[rl], xp);
                atomicAdd(&logit_n[rl], xn);
            }
        }
    }
    __syncthreads();

    if (tid < 32) {
        float bb = b2[0];
        float xp = logit_p[tid] + bb;
        float xn = logit_n[tid] + bb;
        // pos: -log(sigmoid(xp)+eps); neg: -log(1-sigmoid(xn)+eps) = -log(sigmoid(-xn)+eps)
        float term = -logf(1.f / (1.f + expf(-xp)) + 1e-8f)
                     -logf(1.f / (1.f + expf(xn)) + 1e-8f);
        #pragma unroll
        for (int off = 16; off; off >>= 1) term += __shfl_down(term, off);
        if (tid == 0) {
            atomicAdd(acc_out, term);
            __threadfence();
            int done = atomicAdd(hcount, 1);
            if (done == (int)gridDim.x - 1) {
                float total = atomicAdd(acc_out, 0.f);   // all adds fenced-in
                out[0] = total * (1.0f / (2.0f * (float)NB));
            }
        }
    }
}

// ==================== launch ====================
extern "C" void kernel_launch(void* const* d_in, const int* in_sizes, int n_in,
                              void* d_out, int out_size, void* d_ws, size_t ws_size,
                              hipStream_t stream) {
    const float* vcross = (const float*)d_in[0];
    const float* tcross = (const float*)d_in[1];
    const float* vuni   = (const float*)d_in[2];
    const float* tuni   = (const float*)d_in[3];
    const float* W1     = (const float*)d_in[4];
    const float* b1     = (const float*)d_in[5];
    const float* W2     = (const float*)d_in[6];
    const float* b2     = (const float*)d_in[7];

    char* ws = (char*)d_ws;
    float* diag   = (float*)(ws + OFF_DIAG);
    int* neg      = (int*)(ws + OFF_NEG);
    int* mrows    = (int*)(ws + OFF_MROWS);
    float* acc    = (float*)(ws + OFF_ACC);
    int* mcount   = (int*)(ws + OFF_ACC + 4);
    int* hcount   = (int*)(ws + OFF_ACC + 8);
    ushort_t* bp1 = (ushort_t*)(ws + OFF_BP1);
    ushort_t* bp2 = (ushort_t*)(ws + OFF_BP2);
    unsigned long long* fb2 = (unsigned long long*)(ws + OFF_FB2);
    float* diag2  = (float*)(ws + OFF_DIAG2);
    ushort_t* A2  = (ushort_t*)(ws + OFF_A2);
    ushort_t* w1t = (ushort_t*)(ws + OFF_W1T);
    ushort_t* tb  = (ushort_t*)(ws + OFF_TB);
    ushort_t* vb  = (ushort_t*)(ws + OFF_VB);

    const int big = (ws_size >= (size_t)WS_BIG);
    ushort_t* tcb = big ? (ushort_t*)(ws + OFF_TCB) : tb;
    ushort_t* vcb = big ? (ushort_t*)(ws + OFF_VCB) : vb;

    prep_uni_kernel<<<big ? 3104 : 1056, 256, 0, stream>>>(
        tuni, vuni, tcross, vcross, W1, tb, vb, tcb, vcb, w1t, diag,
        (uint32_t*)(ws + OFF_ACC));
    mine_p1_kernel<<<dim3(64, 8), 256, 0, stream>>>(tb, vb, diag, bp1);
    combine_p1_kernel<<<NB / 256, 256, 0, stream>>>(bp1, diag, tb, neg, mrows, mcount, A2, diag2);
    mine_p2_kernel<<<dim3(8, 64), 256, 0, stream>>>(A2, vb, diag2, mrows, mcount, bp2, fb2);
    if (!big)
        prep_head_kernel<<<2048, 256, 0, stream>>>(tcross, vcross, tb, vb);
    head4_kernel<<<NB / 32, 256, 0, stream>>>(tcb, vcb, w1t, neg, bp2, fb2,
                                              tcross, vcross, W1, b1, W2, b2,
                                              acc, hcount, (float*)d_out);
}

// Round 15
// 68.888 us; speedup vs baseline: 1.2079x; 1.0561x over previous
//
#include <hip/hip_runtime.h>
#include <stdint.h>

#define NB 8192
#define DD 256

typedef unsigned short ushort_t;
typedef __attribute__((ext_vector_type(8))) short bf16x8;
typedef __attribute__((ext_vector_type(4))) float f32x4;

// ==================== workspace layout (<= proven 10039296) ====================
#define OFF_DIAG   0          // f32[8192]
#define OFF_NEG    32768      // int[8192]
#define OFF_MROWS  65536      // int[1024]
#define OFF_ACC    69632      // f32 acc @+0, int mcount @+4, int hcount @+8
#define OFF_BP1    73728      // u16[8][8192]   (128 KB)
#define OFF_BP2    204800     // u16[64][1024]  (128 KB)
#define OFF_FB2    335872     // u64[64][1024]  (512 KB)
#define OFF_DIAG2  860160     // f32[1024]
#define OFF_A2     864256     // bf16[1024][256] (512 KB, swizzled by slot)
#define OFF_W1T    1388544    // bf16[256][512]  (256 KB, swizzled)
#define OFF_TB     1650688    // bf16[8192][256] (4 MB, swizzled)
#define OFF_VB     5844992    // bf16[8192][256] (4 MB, swizzled) -> end 10039296

__device__ __forceinline__ unsigned short f2bf(float x) {
    uint32_t u = __float_as_uint(x);
    return (unsigned short)((u + 0x7FFFu + ((u >> 16) & 1u)) >> 16);
}

__device__ __forceinline__ uint4 packbf8(float4 x, float4 y) {
    uint4 o;
    o.x = (uint32_t)f2bf(x.x) | ((uint32_t)f2bf(x.y) << 16);
    o.y = (uint32_t)f2bf(x.z) | ((uint32_t)f2bf(x.w) << 16);
    o.z = (uint32_t)f2bf(y.x) | ((uint32_t)f2bf(y.y) << 16);
    o.w = (uint32_t)f2bf(y.z) | ((uint32_t)f2bf(y.w) << 16);
    return o;
}

__device__ __forceinline__ unsigned fkey(float s) {
    unsigned u = __float_as_uint(s);
    return (u & 0x80000000u) ? ~u : (u | 0x80000000u);
}

// ---------------- prep_uni: fused cvt(t,v)+diag, W1T, zero-init (proven R14) ----------------
__global__ __launch_bounds__(256) void prep_uni_kernel(const float* __restrict__ t,
                                                       const float* __restrict__ v,
                                                       const float* __restrict__ W1,
                                                       ushort_t* __restrict__ tb,
                                                       ushort_t* __restrict__ vb,
                                                       ushort_t* __restrict__ W1T,
                                                       float* __restrict__ diag,
                                                       uint32_t* __restrict__ zeroRegion) {
    const int b = blockIdx.x;
    const int tid = threadIdx.x;
    if (b < 1024) {
        // fused: cvt t & v rows 8b..8b+7 (swizzled) + diag partials
        if (b == 0 && tid < 3) zeroRegion[tid] = 0;     // acc + mcount + hcount
        int r = b * 8 + (tid >> 5);
        int cw = tid & 31, kb = cw >> 3, c = cw & 7;
        int csrc = c ^ (r & 7);
        const float4* ts = (const float4*)(t + (size_t)r * DD + kb * 64 + csrc * 8);
        const float4* vs = (const float4*)(v + (size_t)r * DD + kb * 64 + csrc * 8);
        float4 t0 = ts[0], t1 = ts[1];
        float4 v0 = vs[0], v1 = vs[1];
        ((uint4*)tb)[(size_t)r * 32 + cw] = packbf8(t0, t1);
        ((uint4*)vb)[(size_t)r * 32 + cw] = packbf8(v0, v1);
        float s = t0.x * v0.x + t0.y * v0.y + t0.z * v0.z + t0.w * v0.w
                + t1.x * v1.x + t1.y * v1.y + t1.z * v1.z + t1.w * v1.w;
        #pragma unroll
        for (int off = 1; off < 32; off <<= 1) s += __shfl_xor(s, off);
        if ((tid & 31) == 0) diag[r] = s;
    } else {
        // W1T[n][k] = bf16(W1[k][n]), chunk-swizzled by n&7 within each 64-k block
        __shared__ float Ls[64][68];
        int tt = b - 1024;                          // 0..31
        int kb = tt >> 2, nb = tt & 3;
        int r = tid >> 2, q4 = tid & 3;
        #pragma unroll
        for (int j = 0; j < 4; j++) {
            float4 x = *(const float4*)(W1 + (size_t)(kb * 64 + r) * DD + nb * 64 + q4 * 16 + j * 4);
            *(float4*)&Ls[r][q4 * 16 + j * 4] = x;
        }
        __syncthreads();
        int rn = tid >> 2, cq = (tid & 3) * 2;
        #pragma unroll
        for (int cc = 0; cc < 2; cc++) {
            int c = cq + cc;
            int csrc = c ^ (rn & 7);
            float4 x, y;
            x.x = Ls[csrc * 8 + 0][rn]; x.y = Ls[csrc * 8 + 1][rn];
            x.z = Ls[csrc * 8 + 2][rn]; x.w = Ls[csrc * 8 + 3][rn];
            y.x = Ls[csrc * 8 + 4][rn]; y.y = Ls[csrc * 8 + 5][rn];
            y.z = Ls[csrc * 8 + 6][rn]; y.w = Ls[csrc * 8 + 7][rn];
            *(uint4*)&W1T[(size_t)(nb * 64 + rn) * 512 + kb * 64 + c * 8] = packbf8(x, y);
        }
    }
}

// ---------------- shared B-staging (proven R7) ----------------
__device__ __forceinline__ void stage_b(const ushort_t* __restrict__ VB, ushort_t* Bs,
                                        int colBase, int kc, int tid) {
    #pragma unroll
    for (int i = 0; i < 4; ++i) {
        int idx = i * 256 + tid;              // 0..1023
        int r = idx >> 3, c8 = idx & 7;       // source pre-swizzled -> linear copy
        __builtin_amdgcn_global_load_lds(
            (const __attribute__((address_space(1))) uint32_t*)(VB + (size_t)(colBase + r) * DD + kc + c8 * 8),
            (__attribute__((address_space(3))) uint32_t*)(Bs + idx * 8), 16, 0, 0);
    }
}

// ---------------- mine_p1: prefix cols [0,1024) (proven R9) ----------------
__global__ __launch_bounds__(256, 4) void mine_p1_kernel(const ushort_t* __restrict__ TB,
                                                         const ushort_t* __restrict__ VB,
                                                         const float* __restrict__ diag,
                                                         ushort_t* __restrict__ bp1) {
    __shared__ ushort_t Bs[2][128 * 64];       // 32 KB
    __shared__ float diag_s[128];

    const int tid = threadIdx.x;
    const int rowBase = blockIdx.x * 128;
    const int colBase = blockIdx.y * 128;      // y < 8
    const int lane = tid & 63;
    const int wave = tid >> 6;
    const int wr = wave >> 1, wc = wave & 1;
    const int lo = lane & 15, hi = lane >> 4;
    const int lx = lo & 7;

    if (tid < 128) diag_s[tid] = diag[rowBase + tid];

    f32x4 acc[4][4];
    #pragma unroll
    for (int m = 0; m < 4; m++)
        #pragma unroll
        for (int n = 0; n < 4; n++) acc[m][n] = (f32x4){0.f, 0.f, 0.f, 0.f};

    const ushort_t* Abase = TB + (size_t)(rowBase + wr * 64 + lo) * DD;

    stage_b(VB, Bs[0], colBase, 0, tid);
    __syncthreads();

    for (int kt = 0; kt < 4; ++kt) {
        const int buf = kt & 1;
        if (kt < 3)
            stage_b(VB, Bs[buf ^ 1], colBase, (kt + 1) * 64, tid);
        #pragma unroll
        for (int ksl = 0; ksl < 2; ksl++) {
            const int ch = ((((ksl << 2) | hi) ^ lx) << 3);
            bf16x8 a[4], b[4];
            #pragma unroll
            for (int m = 0; m < 4; m++)
                a[m] = *(const bf16x8*)(Abase + (size_t)m * 16 * DD + kt * 64 + ch);
            #pragma unroll
            for (int n = 0; n < 4; n++)
                b[n] = *(const bf16x8*)&Bs[buf][(wc * 64 + n * 16 + lo) * 64 + ch];
            #pragma unroll
            for (int m = 0; m < 4; m++)
                #pragma unroll
                for (int n = 0; n < 4; n++)
                    acc[m][n] = __builtin_amdgcn_mfma_f32_16x16x32_bf16(a[m], b[n], acc[m][n], 0, 0, 0);
        }
        __syncthreads();
    }

    #pragma unroll
    for (int m = 0; m < 4; m++) {
        #pragma unroll
        for (int q = 0; q < 4; q++) {
            const int rl = wr * 64 + m * 16 + hi * 4 + q;
            const int grow = rowBase + rl;
            const float c0 = diag_s[rl] - 0.35f;
            int bm = 0x7FFFFFFF;
            #pragma unroll
            for (int n = 0; n < 4; n++) {
                const float tt = acc[m][n][q] - c0;
                const int gcol = colBase + wc * 64 + n * 16 + lo;
                int cand = (fabsf(tt) < 0.15f && gcol != grow) ? gcol : 0x7FFFFFFF;
                bm = min(bm, cand);
            }
            #pragma unroll
            for (int off = 1; off < 16; off <<= 1) bm = min(bm, __shfl_xor(bm, off));
            if (lo == 0)
                bp1[blockIdx.y * NB + grow] = (ushort_t)min(bm, 0xFFFF);
        }
    }
}

// ---------------- combine_p1 (+absorbed gather): prefix min; missing rows -> slot + panel copy ----------------
__global__ __launch_bounds__(256) void combine_p1_kernel(const ushort_t* __restrict__ bp1,
                                                         const float* __restrict__ diag,
                                                         const ushort_t* __restrict__ TB,
                                                         int* __restrict__ neg,
                                                         int* __restrict__ mrows,
                                                         int* __restrict__ mcount,
                                                         ushort_t* __restrict__ A2,
                                                         float* __restrict__ diag2) {
    int row = blockIdx.x * 256 + threadIdx.x;
    int bmin = 0xFFFF;
    #pragma unroll
    for (int g = 0; g < 8; g++) bmin = min(bmin, (int)bp1[g * NB + row]);
    if (bmin < 0xFFFF) {
        neg[row] = bmin;
    } else {
        int i = atomicAdd(mcount, 1);
        if (i < 1024) {
            mrows[i] = row;
            neg[row] = -(i + 1);                // resolved in head5
            diag2[i] = diag[row];
            // copy row panel tb[row] -> A2[i], re-key swizzle (row&7 -> i&7)
            const uint4* src = (const uint4*)(TB + (size_t)row * DD);
            uint4* dst = (uint4*)(A2 + (size_t)i * DD);
            int kx = (i ^ row) & 7;
            #pragma unroll
            for (int cw = 0; cw < 32; cw++) {
                int kb = cw >> 3, c = cw & 7;
                dst[kb * 8 + c] = src[kb * 8 + (c ^ kx)];
            }
        } else {
            neg[row] = (row + 4096) & (NB - 1); // overflow placeholder (P ~ 0)
        }
    }
}

// ---------------- mine_p2: missing rows x all cols; band-min + argmax fallback (proven R9) ----------------
__global__ __launch_bounds__(256, 3) void mine_p2_kernel(const ushort_t* __restrict__ A2,
                                                         const ushort_t* __restrict__ VB,
                                                         const float* __restrict__ diag2,
                                                         const int* __restrict__ mrows,
                                                         const int* __restrict__ mcount,
                                                         ushort_t* __restrict__ bp2,
                                                         unsigned long long* __restrict__ fb2) {
    const int slotBase = blockIdx.x * 128;
    const int count = min(mcount[0], 1024);
    if (slotBase >= count) return;              // uniform early-out for inactive panels

    __shared__ ushort_t Bs[2][128 * 64];
    __shared__ float diag_s[128];
    __shared__ int rows_s[128];

    const int tid = threadIdx.x;
    const int colBase = blockIdx.y * 128;       // y < 64
    const int lane = tid & 63;
    const int wave = tid >> 6;
    const int wr = wave >> 1, wc = wave & 1;
    const int lo = lane & 15, hi = lane >> 4;
    const int lx = lo & 7;

    if (tid < 128) {
        diag_s[tid] = diag2[slotBase + tid];
        rows_s[tid] = mrows[slotBase + tid];    // garbage for pad slots; results discarded
    }

    f32x4 acc[4][4];
    #pragma unroll
    for (int m = 0; m < 4; m++)
        #pragma unroll
        for (int n = 0; n < 4; n++) acc[m][n] = (f32x4){0.f, 0.f, 0.f, 0.f};

    const ushort_t* Abase = A2 + (size_t)(slotBase + wr * 64 + lo) * DD;

    stage_b(VB, Bs[0], colBase, 0, tid);
    __syncthreads();

    for (int kt = 0; kt < 4; ++kt) {
        const int buf = kt & 1;
        if (kt < 3)
            stage_b(VB, Bs[buf ^ 1], colBase, (kt + 1) * 64, tid);
        #pragma unroll
        for (int ksl = 0; ksl < 2; ksl++) {
            const int ch = ((((ksl << 2) | hi) ^ lx) << 3);
            bf16x8 a[4], b[4];
            #pragma unroll
            for (int m = 0; m < 4; m++)
                a[m] = *(const bf16x8*)(Abase + (size_t)m * 16 * DD + kt * 64 + ch);
            #pragma unroll
            for (int n = 0; n < 4; n++)
                b[n] = *(const bf16x8*)&Bs[buf][(wc * 64 + n * 16 + lo) * 64 + ch];
            #pragma unroll
            for (int m = 0; m < 4; m++)
                #pragma unroll
                for (int n = 0; n < 4; n++)
                    acc[m][n] = __builtin_amdgcn_mfma_f32_16x16x32_bf16(a[m], b[n], acc[m][n], 0, 0, 0);
        }
        __syncthreads();
    }

    #pragma unroll
    for (int m = 0; m < 4; m++) {
        #pragma unroll
        for (int q = 0; q < 4; q++) {
            const int rl = wr * 64 + m * 16 + hi * 4 + q;
            const int actual = rows_s[rl];
            const float c0 = diag_s[rl] - 0.35f;
            int bm = 0x7FFFFFFF;
            unsigned long long pk = 0ULL;
            #pragma unroll
            for (int n = 0; n < 4; n++) {
                const float s = acc[m][n][q];
                const int gcol = colBase + wc * 64 + n * 16 + lo;
                if (gcol != actual) {
                    unsigned long long p = ((unsigned long long)fkey(s) << 32) | (unsigned)(NB - 1 - gcol);
                    pk = (p > pk) ? p : pk;
                    if (fabsf(s - c0) < 0.15f) bm = min(bm, gcol);
                }
            }
            #pragma unroll
            for (int off = 1; off < 16; off <<= 1) {
                unsigned long long po = __shfl_xor(pk, off);
                int bo = __shfl_xor(bm, off);
                pk = (po > pk) ? po : pk;
                bm = min(bm, bo);
            }
            if (lo == 0) {
                bp2[blockIdx.y * 1024 + slotBase + rl] = (ushort_t)min(bm, 0xFFFF);
                fb2[blockIdx.y * 1024 + slotBase + rl] = pk;
            }
        }
    }
}

// ==================== head5: head4 with reg-staged A from raw f32 (T14 split) ====================
// B (W1T) staging unchanged (glds). A: f32 loads issued BEFORE MFMA, cvt+ds_write AFTER.
// LDS layout identical to head4: slot (r, c8) holds logical chunk c8^(r&7).
__device__ __forceinline__ void stage_B5(const ushort_t* __restrict__ W1T, ushort_t* Bs,
                                         int kc, int tid) {
    #pragma unroll
    for (int i = 0; i < 8; ++i) {                 // 256 cols x 64 k
        int idx = i * 256 + tid;
        int n = idx >> 3, c8 = idx & 7;
        __builtin_amdgcn_global_load_lds(
            (const __attribute__((address_space(1))) uint32_t*)(W1T + (size_t)n * 512 + kc + c8 * 8),
            (__attribute__((address_space(3))) uint32_t*)(Bs + idx * 8), 16, 0, 0);
    }
}

__global__ __launch_bounds__(256) void head5_kernel(const ushort_t* __restrict__ W1T,
                                                    const int* __restrict__ neg,
                                                    const ushort_t* __restrict__ bp2,
                                                    const unsigned long long* __restrict__ fb2,
                                                    const float* __restrict__ tcf,
                                                    const float* __restrict__ vcf,
                                                    const float* __restrict__ W1,
                                                    const float* __restrict__ b1,
                                                    const float* __restrict__ W2,
                                                    const float* __restrict__ b2,
                                                    float* __restrict__ acc_out,
                                                    int* __restrict__ hcount,
                                                    float* __restrict__ out) {
    __shared__ ushort_t As[2][64 * 64];           // 8 KB x2
    __shared__ ushort_t Bs[2][256 * 64];          // 32 KB x2
    __shared__ int neg_l[32];
    __shared__ float dotp_l[32], dotn_l[32];
    __shared__ float logit_p[32], logit_n[32];

    const int tid = threadIdx.x;
    const int rowBase = blockIdx.x * 32;
    const int lane = tid & 63;
    const int wcv = tid >> 6;                     // wave = col group (4 x 64 cols)
    const int lo = lane & 15, hi = lane >> 4;
    const int lx = lo & 7;

    // resolve missing neg rows (proven R13)
    if (tid < 32) {
        int grow = rowBase + tid;
        int nv = neg[grow];
        if (nv < 0) {
            int s = -nv - 1;
            int bmin = 0xFFFF;
            unsigned long long pk = 0ULL;
            #pragma unroll
            for (int g = 0; g < 64; g++) {
                bmin = min(bmin, (int)bp2[g * 1024 + s]);
                unsigned long long f = fb2[g * 1024 + s];
                pk = (f > pk) ? f : pk;
            }
            nv = (bmin < 0xFFFF) ? bmin : (NB - 1 - (int)(unsigned)(pk & 0xFFFFFFFFull));
        }
        neg_l[tid] = nv;
        logit_p[tid] = 0.f;
        logit_n[tid] = 0.f;
    }

    // prologue: issue B glds for kt=0; A t-chunk f32 loads (1 chunk/thread)
    stage_B5(W1T, Bs[0], 0, tid);
    float4 p0, p1;
    {
        int r = tid >> 3, c8 = tid & 7;
        int lc = c8 ^ (r & 7);                    // logical chunk (write pre-swizzled)
        const float4* src = (const float4*)(tcf + (size_t)(rowBase + r) * DD + 0 + lc * 8);
        p0 = src[0]; p1 = src[1];
    }

    // dot features (fp32 exact), 8 threads/row, both pos & neg
    __syncthreads();                              // neg_l visible (also covers logit init)
    {
        int r = tid >> 3, e = tid & 7;
        int grow = rowBase + r;
        int vn = neg_l[r];
        const float4* tp = (const float4*)(tcf + (size_t)grow * DD + e * 32);
        const float4* vp = (const float4*)(vcf + (size_t)grow * DD + e * 32);
        const float4* vq = (const float4*)(vcf + (size_t)vn * DD + e * 32);
        float sp = 0.f, sn = 0.f;
        #pragma unroll
        for (int j = 0; j < 8; j++) {
            float4 a = tp[j], v = vp[j], w = vq[j];
            sp += a.x * v.x + a.y * v.y + a.z * v.z + a.w * v.w;
            sn += a.x * w.x + a.y * w.y + a.z * w.z + a.w * w.w;
        }
        #pragma unroll
        for (int off = 1; off < 8; off <<= 1) {
            sp += __shfl_xor(sp, off);
            sn += __shfl_xor(sn, off);
        }
        if (e == 0) { dotp_l[r] = sp; dotn_l[r] = sn; }
    }

    // write prologue A chunk (already swizzled layout)
    *(uint4*)(As[0] + tid * 8) = packbf8(p0, p1);

    f32x4 acc_t[2][4], acc_p[2][4], acc_n[2][4];
    #pragma unroll
    for (int m = 0; m < 2; m++)
        #pragma unroll
        for (int n = 0; n < 4; n++) {
            acc_t[m][n] = (f32x4){0.f, 0.f, 0.f, 0.f};
            acc_p[m][n] = (f32x4){0.f, 0.f, 0.f, 0.f};
            acc_n[m][n] = (f32x4){0.f, 0.f, 0.f, 0.f};
        }

    __syncthreads();                              // drains B glds(0) + As[0] writes + dot stores

    for (int kt = 0; kt < 8; ++kt) {
        const int buf = kt & 1;
        // (1) issue A f32 loads for kt+1 into regs; (2) issue B glds for kt+1
        float4 a00, a01, a10, a11;
        if (kt < 7) {
            const int kc = (kt + 1) * 64;
            if (kc < 256) {                       // t-phase staging: 1 chunk/thread
                int r = tid >> 3, c8 = tid & 7;
                int lc = c8 ^ (r & 7);
                const float4* src = (const float4*)(tcf + (size_t)(rowBase + r) * DD + kc + lc * 8);
                a00 = src[0]; a01 = src[1];
            } else {                              // v-phase staging: 2 chunks/thread (own + neg rows)
                int r0 = tid >> 3, c80 = tid & 7;
                int lc0 = c80 ^ (r0 & 7);
                const float4* s0 = (const float4*)(vcf + (size_t)(rowBase + r0) * DD + (kc - 256) + lc0 * 8);
                a00 = s0[0]; a01 = s0[1];
                int idx = 256 + tid;
                int r1 = idx >> 3, c81 = idx & 7;  // 32..63
                int rr = neg_l[r1 - 32];
                int lc1 = c81 ^ (r1 & 7);
                const float4* s1 = (const float4*)(vcf + (size_t)rr * DD + (kc - 256) + lc1 * 8);
                a10 = s1[0]; a11 = s1[1];
            }
            stage_B5(W1T, Bs[buf ^ 1], kc, tid);
        }
        // (3) MFMA block on As[buf], Bs[buf] — byte-identical to proven head4
        #pragma unroll
        for (int ksl = 0; ksl < 2; ksl++) {
            const int ch = ((((ksl << 2) | hi) ^ lx) << 3);
            bf16x8 b[4];
            #pragma unroll
            for (int n = 0; n < 4; n++)
                b[n] = *(const bf16x8*)&Bs[buf][(wcv * 64 + n * 16 + lo) * 64 + ch];
            if (kt < 4) {                         // t-phase -> acc_t
                bf16x8 a[2];
                #pragma unroll
                for (int m = 0; m < 2; m++)
                    a[m] = *(const bf16x8*)&As[buf][(m * 16 + lo) * 64 + ch];
                #pragma unroll
                for (int m = 0; m < 2; m++)
                    #pragma unroll
                    for (int n = 0; n < 4; n++)
                        acc_t[m][n] = __builtin_amdgcn_mfma_f32_16x16x32_bf16(a[m], b[n], acc_t[m][n], 0, 0, 0);
            } else {                              // v-phase -> acc_p (rows 0-31) + acc_n (rows 32-63)
                bf16x8 ap[2], an[2];
                #pragma unroll
                for (int m = 0; m < 2; m++) {
                    ap[m] = *(const bf16x8*)&As[buf][(m * 16 + lo) * 64 + ch];
                    an[m] = *(const bf16x8*)&As[buf][(32 + m * 16 + lo) * 64 + ch];
                }
                #pragma unroll
                for (int m = 0; m < 2; m++)
                    #pragma unroll
                    for (int n = 0; n < 4; n++) {
                        acc_p[m][n] = __builtin_amdgcn_mfma_f32_16x16x32_bf16(ap[m], b[n], acc_p[m][n], 0, 0, 0);
                        acc_n[m][n] = __builtin_amdgcn_mfma_f32_16x16x32_bf16(an[m], b[n], acc_n[m][n], 0, 0, 0);
                    }
            }
        }
        // (4) cvt + ds_write A for kt+1 into As[buf^1]
        if (kt < 7) {
            const int kc = (kt + 1) * 64;
            *(uint4*)(As[buf ^ 1] + tid * 8) = packbf8(a00, a01);
            if (kc >= 256)
                *(uint4*)(As[buf ^ 1] + (256 + tid) * 8) = packbf8(a10, a11);
        }
        __syncthreads();
    }

    // epilogue: h = relu(acc_t + acc_v + b1 + dot*W1[512]); logit = h @ W2 (proven R13)
    float b1v[4], w5v[4], w2v[4];
    #pragma unroll
    for (int n = 0; n < 4; n++) {
        int cl = wcv * 64 + n * 16 + lo;
        b1v[n] = b1[cl];
        w5v[n] = W1[(size_t)512 * DD + cl];
        w2v[n] = W2[cl];
    }
    #pragma unroll
    for (int m = 0; m < 2; m++) {
        #pragma unroll
        for (int q = 0; q < 4; q++) {
            const int rl = m * 16 + hi * 4 + q;
            const float dtp = dotp_l[rl], dtn = dotn_l[rl];
            float xp = 0.f, xn = 0.f;
            #pragma unroll
            for (int n = 0; n < 4; n++) {
                float base = acc_t[m][n][q] + b1v[n];
                float hp = base + acc_p[m][n][q] + dtp * w5v[n];
                float hn = base + acc_n[m][n][q] + dtn * w5v[n];
                xp += fmaxf(hp, 0.f) * w2v[n];
                xn += fmaxf(hn, 0.f) * w2v[n];
            }
            #pragma unroll
            for (int off = 1; off < 16; off <<= 1) {
                xp += __shfl_xor(xp, off);
                xn += __shfl_xor(xn, off);
            }
            if (lo == 0) {
                atomicAdd(&logit_p[rl], xp);
                atomicAdd(&logit_n[rl], xn);
            }
        }
    }
    __syncthreads();

    if (tid < 32) {
        float bb = b2[0];
        float xp = logit_p[tid] + bb;
        float xn = logit_n[tid] + bb;
        // pos: -log(sigmoid(xp)+eps); neg: -log(1-sigmoid(xn)+eps) = -log(sigmoid(-xn)+eps)
        float term = -logf(1.f / (1.f + expf(-xp)) + 1e-8f)
                     -logf(1.f / (1.f + expf(xn)) + 1e-8f);
        #pragma unroll
        for (int off = 16; off; off >>= 1) term += __shfl_down(term, off);
        if (tid == 0) {
            atomicAdd(acc_out, term);
            __threadfence();
            int done = atomicAdd(hcount, 1);
            if (done == (int)gridDim.x - 1) {
                float total = atomicAdd(acc_out, 0.f);   // all adds fenced-in
                out[0] = total * (1.0f / (2.0f * (float)NB));
            }
        }
    }
}

// ==================== launch (5 dispatches) ====================
extern "C" void kernel_launch(void* const* d_in, const int* in_sizes, int n_in,
                              void* d_out, int out_size, void* d_ws, size_t ws_size,
                              hipStream_t stream) {
    const float* vcross = (const float*)d_in[0];
    const float* tcross = (const float*)d_in[1];
    const float* vuni   = (const float*)d_in[2];
    const float* tuni   = (const float*)d_in[3];
    const float* W1     = (const float*)d_in[4];
    const float* b1     = (const float*)d_in[5];
    const float* W2     = (const float*)d_in[6];
    const float* b2     = (const float*)d_in[7];

    char* ws = (char*)d_ws;
    float* diag   = (float*)(ws + OFF_DIAG);
    int* neg      = (int*)(ws + OFF_NEG);
    int* mrows    = (int*)(ws + OFF_MROWS);
    float* acc    = (float*)(ws + OFF_ACC);
    int* mcount   = (int*)(ws + OFF_ACC + 4);
    int* hcount   = (int*)(ws + OFF_ACC + 8);
    ushort_t* bp1 = (ushort_t*)(ws + OFF_BP1);
    ushort_t* bp2 = (ushort_t*)(ws + OFF_BP2);
    unsigned long long* fb2 = (unsigned long long*)(ws + OFF_FB2);
    float* diag2  = (float*)(ws + OFF_DIAG2);
    ushort_t* A2  = (ushort_t*)(ws + OFF_A2);
    ushort_t* w1t = (ushort_t*)(ws + OFF_W1T);
    ushort_t* tb  = (ushort_t*)(ws + OFF_TB);
    ushort_t* vb  = (ushort_t*)(ws + OFF_VB);

    prep_uni_kernel<<<1056, 256, 0, stream>>>(tuni, vuni, W1, tb, vb, w1t, diag,
                                              (uint32_t*)(ws + OFF_ACC));
    mine_p1_kernel<<<dim3(64, 8), 256, 0, stream>>>(tb, vb, diag, bp1);
    combine_p1_kernel<<<NB / 256, 256, 0, stream>>>(bp1, diag, tb, neg, mrows, mcount, A2, diag2);
    mine_p2_kernel<<<dim3(8, 64), 256, 0, stream>>>(A2, vb, diag2, mrows, mcount, bp2, fb2);
    head5_kernel<<<NB / 32, 256, 0, stream>>>(w1t, neg, bp2, fb2,
                                              tcross, vcross, W1, b1, W2, b2,
                                              acc, hcount, (float*)d_out);
}

// Round 16
// 67.639 us; speedup vs baseline: 1.2302x; 1.0185x over previous
//
#include <hip/hip_runtime.h>
#include <stdint.h>

#define NB 8192
#define DD 256
#define PREFIX 512            // prefix cols mined in pass 1 (R16: 1024 -> 512)
#define NPART (PREFIX / 128)  // 4 col-groups

typedef unsigned short ushort_t;
typedef __attribute__((ext_vector_type(8))) short bf16x8;
typedef __attribute__((ext_vector_type(4))) float f32x4;

// ==================== workspace layout (<= proven 10039296) ====================
#define OFF_DIAG   0          // f32[8192]
#define OFF_NEG    32768      // int[8192]
#define OFF_MROWS  65536      // int[1024]
#define OFF_ACC    69632      // f32 acc @+0, int mcount @+4, int hcount @+8
#define OFF_BP1    73728      // u16[NPART][8192] (64 KB used of 128 KB region)
#define OFF_BP2    204800     // u16[64][1024]  (128 KB)
#define OFF_FB2    335872     // u64[64][1024]  (512 KB)
#define OFF_DIAG2  860160     // f32[1024]
#define OFF_A2     864256     // bf16[1024][256] (512 KB, swizzled by slot)
#define OFF_W1T    1388544    // bf16[256][512]  (256 KB, swizzled)
#define OFF_TB     1650688    // bf16[8192][256] (4 MB, swizzled)
#define OFF_VB     5844992    // bf16[8192][256] (4 MB, swizzled) -> end 10039296

__device__ __forceinline__ unsigned short f2bf(float x) {
    uint32_t u = __float_as_uint(x);
    return (unsigned short)((u + 0x7FFFu + ((u >> 16) & 1u)) >> 16);
}

__device__ __forceinline__ uint4 packbf8(float4 x, float4 y) {
    uint4 o;
    o.x = (uint32_t)f2bf(x.x) | ((uint32_t)f2bf(x.y) << 16);
    o.y = (uint32_t)f2bf(x.z) | ((uint32_t)f2bf(x.w) << 16);
    o.z = (uint32_t)f2bf(y.x) | ((uint32_t)f2bf(y.y) << 16);
    o.w = (uint32_t)f2bf(y.z) | ((uint32_t)f2bf(y.w) << 16);
    return o;
}

__device__ __forceinline__ unsigned fkey(float s) {
    unsigned u = __float_as_uint(s);
    return (u & 0x80000000u) ? ~u : (u | 0x80000000u);
}

// ---------------- prep_uni: fused cvt(t,v)+diag, W1T, zero-init (proven R14) ----------------
__global__ __launch_bounds__(256) void prep_uni_kernel(const float* __restrict__ t,
                                                       const float* __restrict__ v,
                                                       const float* __restrict__ W1,
                                                       ushort_t* __restrict__ tb,
                                                       ushort_t* __restrict__ vb,
                                                       ushort_t* __restrict__ W1T,
                                                       float* __restrict__ diag,
                                                       uint32_t* __restrict__ zeroRegion) {
    const int b = blockIdx.x;
    const int tid = threadIdx.x;
    if (b < 1024) {
        // fused: cvt t & v rows 8b..8b+7 (swizzled) + diag partials
        if (b == 0 && tid < 3) zeroRegion[tid] = 0;     // acc + mcount + hcount
        int r = b * 8 + (tid >> 5);
        int cw = tid & 31, kb = cw >> 3, c = cw & 7;
        int csrc = c ^ (r & 7);
        const float4* ts = (const float4*)(t + (size_t)r * DD + kb * 64 + csrc * 8);
        const float4* vs = (const float4*)(v + (size_t)r * DD + kb * 64 + csrc * 8);
        float4 t0 = ts[0], t1 = ts[1];
        float4 v0 = vs[0], v1 = vs[1];
        ((uint4*)tb)[(size_t)r * 32 + cw] = packbf8(t0, t1);
        ((uint4*)vb)[(size_t)r * 32 + cw] = packbf8(v0, v1);
        float s = t0.x * v0.x + t0.y * v0.y + t0.z * v0.z + t0.w * v0.w
                + t1.x * v1.x + t1.y * v1.y + t1.z * v1.z + t1.w * v1.w;
        #pragma unroll
        for (int off = 1; off < 32; off <<= 1) s += __shfl_xor(s, off);
        if ((tid & 31) == 0) diag[r] = s;
    } else {
        // W1T[n][k] = bf16(W1[k][n]), chunk-swizzled by n&7 within each 64-k block
        __shared__ float Ls[64][68];
        int tt = b - 1024;                          // 0..31
        int kb = tt >> 2, nb = tt & 3;
        int r = tid >> 2, q4 = tid & 3;
        #pragma unroll
        for (int j = 0; j < 4; j++) {
            float4 x = *(const float4*)(W1 + (size_t)(kb * 64 + r) * DD + nb * 64 + q4 * 16 + j * 4);
            *(float4*)&Ls[r][q4 * 16 + j * 4] = x;
        }
        __syncthreads();
        int rn = tid >> 2, cq = (tid & 3) * 2;
        #pragma unroll
        for (int cc = 0; cc < 2; cc++) {
            int c = cq + cc;
            int csrc = c ^ (rn & 7);
            float4 x, y;
            x.x = Ls[csrc * 8 + 0][rn]; x.y = Ls[csrc * 8 + 1][rn];
            x.z = Ls[csrc * 8 + 2][rn]; x.w = Ls[csrc * 8 + 3][rn];
            y.x = Ls[csrc * 8 + 4][rn]; y.y = Ls[csrc * 8 + 5][rn];
            y.z = Ls[csrc * 8 + 6][rn]; y.w = Ls[csrc * 8 + 7][rn];
            *(uint4*)&W1T[(size_t)(nb * 64 + rn) * 512 + kb * 64 + c * 8] = packbf8(x, y);
        }
    }
}

// ---------------- shared B-staging (proven R7) ----------------
__device__ __forceinline__ void stage_b(const ushort_t* __restrict__ VB, ushort_t* Bs,
                                        int colBase, int kc, int tid) {
    #pragma unroll
    for (int i = 0; i < 4; ++i) {
        int idx = i * 256 + tid;              // 0..1023
        int r = idx >> 3, c8 = idx & 7;       // source pre-swizzled -> linear copy
        __builtin_amdgcn_global_load_lds(
            (const __attribute__((address_space(1))) uint32_t*)(VB + (size_t)(colBase + r) * DD + kc + c8 * 8),
            (__attribute__((address_space(3))) uint32_t*)(Bs + idx * 8), 16, 0, 0);
    }
}

// ---------------- mine_p1: prefix cols [0,PREFIX) (proven R9, grid y=NPART) ----------------
__global__ __launch_bounds__(256, 4) void mine_p1_kernel(const ushort_t* __restrict__ TB,
                                                         const ushort_t* __restrict__ VB,
                                                         const float* __restrict__ diag,
                                                         ushort_t* __restrict__ bp1) {
    __shared__ ushort_t Bs[2][128 * 64];       // 32 KB
    __shared__ float diag_s[128];

    const int tid = threadIdx.x;
    const int rowBase = blockIdx.x * 128;
    const int colBase = blockIdx.y * 128;      // y < NPART
    const int lane = tid & 63;
    const int wave = tid >> 6;
    const int wr = wave >> 1, wc = wave & 1;
    const int lo = lane & 15, hi = lane >> 4;
    const int lx = lo & 7;

    if (tid < 128) diag_s[tid] = diag[rowBase + tid];

    f32x4 acc[4][4];
    #pragma unroll
    for (int m = 0; m < 4; m++)
        #pragma unroll
        for (int n = 0; n < 4; n++) acc[m][n] = (f32x4){0.f, 0.f, 0.f, 0.f};

    const ushort_t* Abase = TB + (size_t)(rowBase + wr * 64 + lo) * DD;

    stage_b(VB, Bs[0], colBase, 0, tid);
    __syncthreads();

    for (int kt = 0; kt < 4; ++kt) {
        const int buf = kt & 1;
        if (kt < 3)
            stage_b(VB, Bs[buf ^ 1], colBase, (kt + 1) * 64, tid);
        #pragma unroll
        for (int ksl = 0; ksl < 2; ksl++) {
            const int ch = ((((ksl << 2) | hi) ^ lx) << 3);
            bf16x8 a[4], b[4];
            #pragma unroll
            for (int m = 0; m < 4; m++)
                a[m] = *(const bf16x8*)(Abase + (size_t)m * 16 * DD + kt * 64 + ch);
            #pragma unroll
            for (int n = 0; n < 4; n++)
                b[n] = *(const bf16x8*)&Bs[buf][(wc * 64 + n * 16 + lo) * 64 + ch];
            #pragma unroll
            for (int m = 0; m < 4; m++)
                #pragma unroll
                for (int n = 0; n < 4; n++)
                    acc[m][n] = __builtin_amdgcn_mfma_f32_16x16x32_bf16(a[m], b[n], acc[m][n], 0, 0, 0);
        }
        __syncthreads();
    }

    #pragma unroll
    for (int m = 0; m < 4; m++) {
        #pragma unroll
        for (int q = 0; q < 4; q++) {
            const int rl = wr * 64 + m * 16 + hi * 4 + q;
            const int grow = rowBase + rl;
            const float c0 = diag_s[rl] - 0.35f;
            int bm = 0x7FFFFFFF;
            #pragma unroll
            for (int n = 0; n < 4; n++) {
                const float tt = acc[m][n][q] - c0;
                const int gcol = colBase + wc * 64 + n * 16 + lo;
                int cand = (fabsf(tt) < 0.15f && gcol != grow) ? gcol : 0x7FFFFFFF;
                bm = min(bm, cand);
            }
            #pragma unroll
            for (int off = 1; off < 16; off <<= 1) bm = min(bm, __shfl_xor(bm, off));
            if (lo == 0)
                bp1[blockIdx.y * NB + grow] = (ushort_t)min(bm, 0xFFFF);
        }
    }
}

// ---------------- combine_p1 (+absorbed gather): prefix min; missing rows -> slot + panel copy ----------------
__global__ __launch_bounds__(256) void combine_p1_kernel(const ushort_t* __restrict__ bp1,
                                                         const float* __restrict__ diag,
                                                         const ushort_t* __restrict__ TB,
                                                         int* __restrict__ neg,
                                                         int* __restrict__ mrows,
                                                         int* __restrict__ mcount,
                                                         ushort_t* __restrict__ A2,
                                                         float* __restrict__ diag2) {
    int row = blockIdx.x * 256 + threadIdx.x;
    int bmin = 0xFFFF;
    #pragma unroll
    for (int g = 0; g < NPART; g++) bmin = min(bmin, (int)bp1[g * NB + row]);
    if (bmin < 0xFFFF) {
        neg[row] = bmin;
    } else {
        int i = atomicAdd(mcount, 1);
        if (i < 1024) {
            mrows[i] = row;
            neg[row] = -(i + 1);                // resolved in head5
            diag2[i] = diag[row];
            // copy row panel tb[row] -> A2[i], re-key swizzle (row&7 -> i&7)
            const uint4* src = (const uint4*)(TB + (size_t)row * DD);
            uint4* dst = (uint4*)(A2 + (size_t)i * DD);
            int kx = (i ^ row) & 7;
            #pragma unroll
            for (int cw = 0; cw < 32; cw++) {
                int kb = cw >> 3, c = cw & 7;
                dst[kb * 8 + c] = src[kb * 8 + (c ^ kx)];
            }
        } else {
            neg[row] = (row + 4096) & (NB - 1); // overflow placeholder (P ~ 0)
        }
    }
}

// ---------------- mine_p2: missing rows x all cols; band-min + argmax fallback (proven R9) ----------------
__global__ __launch_bounds__(256, 3) void mine_p2_kernel(const ushort_t* __restrict__ A2,
                                                         const ushort_t* __restrict__ VB,
                                                         const float* __restrict__ diag2,
                                                         const int* __restrict__ mrows,
                                                         const int* __restrict__ mcount,
                                                         ushort_t* __restrict__ bp2,
                                                         unsigned long long* __restrict__ fb2) {
    const int slotBase = blockIdx.x * 128;
    const int count = min(mcount[0], 1024);
    if (slotBase >= count) return;              // uniform early-out for inactive panels

    __shared__ ushort_t Bs[2][128 * 64];
    __shared__ float diag_s[128];
    __shared__ int rows_s[128];

    const int tid = threadIdx.x;
    const int colBase = blockIdx.y * 128;       // y < 64
    const int lane = tid & 63;
    const int wave = tid >> 6;
    const int wr = wave >> 1, wc = wave & 1;
    const int lo = lane & 15, hi = lane >> 4;
    const int lx = lo & 7;

    if (tid < 128) {
        diag_s[tid] = diag2[slotBase + tid];
        rows_s[tid] = mrows[slotBase + tid];    // garbage for pad slots; results discarded
    }

    f32x4 acc[4][4];
    #pragma unroll
    for (int m = 0; m < 4; m++)
        #pragma unroll
        for (int n = 0; n < 4; n++) acc[m][n] = (f32x4){0.f, 0.f, 0.f, 0.f};

    const ushort_t* Abase = A2 + (size_t)(slotBase + wr * 64 + lo) * DD;

    stage_b(VB, Bs[0], colBase, 0, tid);
    __syncthreads();

    for (int kt = 0; kt < 4; ++kt) {
        const int buf = kt & 1;
        if (kt < 3)
            stage_b(VB, Bs[buf ^ 1], colBase, (kt + 1) * 64, tid);
        #pragma unroll
        for (int ksl = 0; ksl < 2; ksl++) {
            const int ch = ((((ksl << 2) | hi) ^ lx) << 3);
            bf16x8 a[4], b[4];
            #pragma unroll
            for (int m = 0; m < 4; m++)
                a[m] = *(const bf16x8*)(Abase + (size_t)m * 16 * DD + kt * 64 + ch);
            #pragma unroll
            for (int n = 0; n < 4; n++)
                b[n] = *(const bf16x8*)&Bs[buf][(wc * 64 + n * 16 + lo) * 64 + ch];
            #pragma unroll
            for (int m = 0; m < 4; m++)
                #pragma unroll
                for (int n = 0; n < 4; n++)
                    acc[m][n] = __builtin_amdgcn_mfma_f32_16x16x32_bf16(a[m], b[n], acc[m][n], 0, 0, 0);
        }
        __syncthreads();
    }

    #pragma unroll
    for (int m = 0; m < 4; m++) {
        #pragma unroll
        for (int q = 0; q < 4; q++) {
            const int rl = wr * 64 + m * 16 + hi * 4 + q;
            const int actual = rows_s[rl];
            const float c0 = diag_s[rl] - 0.35f;
            int bm = 0x7FFFFFFF;
            unsigned long long pk = 0ULL;
            #pragma unroll
            for (int n = 0; n < 4; n++) {
                const float s = acc[m][n][q];
                const int gcol = colBase + wc * 64 + n * 16 + lo;
                if (gcol != actual) {
                    unsigned long long p = ((unsigned long long)fkey(s) << 32) | (unsigned)(NB - 1 - gcol);
                    pk = (p > pk) ? p : pk;
                    if (fabsf(s - c0) < 0.15f) bm = min(bm, gcol);
                }
            }
            #pragma unroll
            for (int off = 1; off < 16; off <<= 1) {
                unsigned long long po = __shfl_xor(pk, off);
                int bo = __shfl_xor(bm, off);
                pk = (po > pk) ? po : pk;
                bm = min(bm, bo);
            }
            if (lo == 0) {
                bp2[blockIdx.y * 1024 + slotBase + rl] = (ushort_t)min(bm, 0xFFFF);
                fb2[blockIdx.y * 1024 + slotBase + rl] = pk;
            }
        }
    }
}

// ==================== head5: reg-staged A from raw f32 (proven R15) ====================
__device__ __forceinline__ void stage_B5(const ushort_t* __restrict__ W1T, ushort_t* Bs,
                                         int kc, int tid) {
    #pragma unroll
    for (int i = 0; i < 8; ++i) {                 // 256 cols x 64 k
        int idx = i * 256 + tid;
        int n = idx >> 3, c8 = idx & 7;
        __builtin_amdgcn_global_load_lds(
            (const __attribute__((address_space(1))) uint32_t*)(W1T + (size_t)n * 512 + kc + c8 * 8),
            (__attribute__((address_space(3))) uint32_t*)(Bs + idx * 8), 16, 0, 0);
    }
}

__global__ __launch_bounds__(256) void head5_kernel(const ushort_t* __restrict__ W1T,
                                                    const int* __restrict__ neg,
                                                    const ushort_t* __restrict__ bp2,
                                                    const unsigned long long* __restrict__ fb2,
                                                    const float* __restrict__ tcf,
                                                    const float* __restrict__ vcf,
                                                    const float* __restrict__ W1,
                                                    const float* __restrict__ b1,
                                                    const float* __restrict__ W2,
                                                    const float* __restrict__ b2,
                                                    float* __restrict__ acc_out,
                                                    int* __restrict__ hcount,
                                                    float* __restrict__ out) {
    __shared__ ushort_t As[2][64 * 64];           // 8 KB x2
    __shared__ ushort_t Bs[2][256 * 64];          // 32 KB x2
    __shared__ int neg_l[32];
    __shared__ float dotp_l[32], dotn_l[32];
    __shared__ float logit_p[32], logit_n[32];

    const int tid = threadIdx.x;
    const int rowBase = blockIdx.x * 32;
    const int lane = tid & 63;
    const int wcv = tid >> 6;                     // wave = col group (4 x 64 cols)
    const int lo = lane & 15, hi = lane >> 4;
    const int lx = lo & 7;

    // resolve missing neg rows (proven R13)
    if (tid < 32) {
        int grow = rowBase + tid;
        int nv = neg[grow];
        if (nv < 0) {
            int s = -nv - 1;
            int bmin = 0xFFFF;
            unsigned long long pk = 0ULL;
            #pragma unroll
            for (int g = 0; g < 64; g++) {
                bmin = min(bmin, (int)bp2[g * 1024 + s]);
                unsigned long long f = fb2[g * 1024 + s];
                pk = (f > pk) ? f : pk;
            }
            nv = (bmin < 0xFFFF) ? bmin : (NB - 1 - (int)(unsigned)(pk & 0xFFFFFFFFull));
        }
        neg_l[tid] = nv;
        logit_p[tid] = 0.f;
        logit_n[tid] = 0.f;
    }

    // prologue: issue B glds for kt=0; A t-chunk f32 loads (1 chunk/thread)
    stage_B5(W1T, Bs[0], 0, tid);
    float4 p0, p1;
    {
        int r = tid >> 3, c8 = tid & 7;
        int lc = c8 ^ (r & 7);                    // logical chunk (write pre-swizzled)
        const float4* src = (const float4*)(tcf + (size_t)(rowBase + r) * DD + 0 + lc * 8);
        p0 = src[0]; p1 = src[1];
    }

    // dot features (fp32 exact), 8 threads/row, both pos & neg
    __syncthreads();                              // neg_l visible (also covers logit init)
    {
        int r = tid >> 3, e = tid & 7;
        int grow = rowBase + r;
        int vn = neg_l[r];
        const float4* tp = (const float4*)(tcf + (size_t)grow * DD + e * 32);
        const float4* vp = (const float4*)(vcf + (size_t)grow * DD + e * 32);
        const float4* vq = (const float4*)(vcf + (size_t)vn * DD + e * 32);
        float sp = 0.f, sn = 0.f;
        #pragma unroll
        for (int j = 0; j < 8; j++) {
            float4 a = tp[j], v = vp[j], w = vq[j];
            sp += a.x * v.x + a.y * v.y + a.z * v.z + a.w * v.w;
            sn += a.x * w.x + a.y * w.y + a.z * w.z + a.w * w.w;
        }
        #pragma unroll
        for (int off = 1; off < 8; off <<= 1) {
            sp += __shfl_xor(sp, off);
            sn += __shfl_xor(sn, off);
        }
        if (e == 0) { dotp_l[r] = sp; dotn_l[r] = sn; }
    }

    // write prologue A chunk (already swizzled layout)
    *(uint4*)(As[0] + tid * 8) = packbf8(p0, p1);

    f32x4 acc_t[2][4], acc_p[2][4], acc_n[2][4];
    #pragma unroll
    for (int m = 0; m < 2; m++)
        #pragma unroll
        for (int n = 0; n < 4; n++) {
            acc_t[m][n] = (f32x4){0.f, 0.f, 0.f, 0.f};
            acc_p[m][n] = (f32x4){0.f, 0.f, 0.f, 0.f};
            acc_n[m][n] = (f32x4){0.f, 0.f, 0.f, 0.f};
        }

    __syncthreads();                              // drains B glds(0) + As[0] writes + dot stores

    for (int kt = 0; kt < 8; ++kt) {
        const int buf = kt & 1;
        // (1) issue A f32 loads for kt+1 into regs; (2) issue B glds for kt+1
        float4 a00, a01, a10, a11;
        if (kt < 7) {
            const int kc = (kt + 1) * 64;
            if (kc < 256) {                       // t-phase staging: 1 chunk/thread
                int r = tid >> 3, c8 = tid & 7;
                int lc = c8 ^ (r & 7);
                const float4* src = (const float4*)(tcf + (size_t)(rowBase + r) * DD + kc + lc * 8);
                a00 = src[0]; a01 = src[1];
            } else {                              // v-phase staging: 2 chunks/thread (own + neg rows)
                int r0 = tid >> 3, c80 = tid & 7;
                int lc0 = c80 ^ (r0 & 7);
                const float4* s0 = (const float4*)(vcf + (size_t)(rowBase + r0) * DD + (kc - 256) + lc0 * 8);
                a00 = s0[0]; a01 = s0[1];
                int idx = 256 + tid;
                int r1 = idx >> 3, c81 = idx & 7;  // 32..63
                int rr = neg_l[r1 - 32];
                int lc1 = c81 ^ (r1 & 7);
                const float4* s1 = (const float4*)(vcf + (size_t)rr * DD + (kc - 256) + lc1 * 8);
                a10 = s1[0]; a11 = s1[1];
            }
            stage_B5(W1T, Bs[buf ^ 1], kc, tid);
        }
        // (3) MFMA block on As[buf], Bs[buf] — byte-identical to proven head4
        #pragma unroll
        for (int ksl = 0; ksl < 2; ksl++) {
            const int ch = ((((ksl << 2) | hi) ^ lx) << 3);
            bf16x8 b[4];
            #pragma unroll
            for (int n = 0; n < 4; n++)
                b[n] = *(const bf16x8*)&Bs[buf][(wcv * 64 + n * 16 + lo) * 64 + ch];
            if (kt < 4) {                         // t-phase -> acc_t
                bf16x8 a[2];
                #pragma unroll
                for (int m = 0; m < 2; m++)
                    a[m] = *(const bf16x8*)&As[buf][(m * 16 + lo) * 64 + ch];
                #pragma unroll
                for (int m = 0; m < 2; m++)
                    #pragma unroll
                    for (int n = 0; n < 4; n++)
                        acc_t[m][n] = __builtin_amdgcn_mfma_f32_16x16x32_bf16(a[m], b[n], acc_t[m][n], 0, 0, 0);
            } else {                              // v-phase -> acc_p (rows 0-31) + acc_n (rows 32-63)
                bf16x8 ap[2], an[2];
                #pragma unroll
                for (int m = 0; m < 2; m++) {
                    ap[m] = *(const bf16x8*)&As[buf][(m * 16 + lo) * 64 + ch];
                    an[m] = *(const bf16x8*)&As[buf][(32 + m * 16 + lo) * 64 + ch];
                }
                #pragma unroll
                for (int m = 0; m < 2; m++)
                    #pragma unroll
                    for (int n = 0; n < 4; n++) {
                        acc_p[m][n] = __builtin_amdgcn_mfma_f32_16x16x32_bf16(ap[m], b[n], acc_p[m][n], 0, 0, 0);
                        acc_n[m][n] = __builtin_amdgcn_mfma_f32_16x16x32_bf16(an[m], b[n], acc_n[m][n], 0, 0, 0);
                    }
            }
        }
        // (4) cvt + ds_write A for kt+1 into As[buf^1]
        if (kt < 7) {
            const int kc = (kt + 1) * 64;
            *(uint4*)(As[buf ^ 1] + tid * 8) = packbf8(a00, a01);
            if (kc >= 256)
                *(uint4*)(As[buf ^ 1] + (256 + tid) * 8) = packbf8(a10, a11);
        }
        __syncthreads();
    }

    // epilogue: h = relu(acc_t + acc_v + b1 + dot*W1[512]); logit = h @ W2 (proven R13)
    float b1v[4], w5v[4], w2v[4];
    #pragma unroll
    for (int n = 0; n < 4; n++) {
        int cl = wcv * 64 + n * 16 + lo;
        b1v[n] = b1[cl];
        w5v[n] = W1[(size_t)512 * DD + cl];
        w2v[n] = W2[cl];
    }
    #pragma unroll
    for (int m = 0; m < 2; m++) {
        #pragma unroll
        for (int q = 0; q < 4; q++) {
            const int rl = m * 16 + hi * 4 + q;
            const float dtp = dotp_l[rl], dtn = dotn_l[rl];
            float xp = 0.f, xn = 0.f;
            #pragma unroll
            for (int n = 0; n < 4; n++) {
                float base = acc_t[m][n][q] + b1v[n];
                float hp = base + acc_p[m][n][q] + dtp * w5v[n];
                float hn = base + acc_n[m][n][q] + dtn * w5v[n];
                xp += fmaxf(hp, 0.f) * w2v[n];
                xn += fmaxf(hn, 0.f) * w2v[n];
            }
            #pragma unroll
            for (int off = 1; off < 16; off <<= 1) {
                xp += __shfl_xor(xp, off);
                xn += __shfl_xor(xn, off);
            }
            if (lo == 0) {
                atomicAdd(&logit_p[rl], xp);
                atomicAdd(&logit_n[rl], xn);
            }
        }
    }
    __syncthreads();

    if (tid < 32) {
        float bb = b2[0];
        float xp = logit_p[tid] + bb;
        float xn = logit_n[tid] + bb;
        // pos: -log(sigmoid(xp)+eps); neg: -log(1-sigmoid(xn)+eps) = -log(sigmoid(-xn)+eps)
        float term = -logf(1.f / (1.f + expf(-xp)) + 1e-8f)
                     -logf(1.f / (1.f + expf(xn)) + 1e-8f);
        #pragma unroll
        for (int off = 16; off; off >>= 1) term += __shfl_down(term, off);
        if (tid == 0) {
            atomicAdd(acc_out, term);
            __threadfence();
            int done = atomicAdd(hcount, 1);
            if (done == (int)gridDim.x - 1) {
                float total = atomicAdd(acc_out, 0.f);   // all adds fenced-in
                out[0] = total * (1.0f / (2.0f * (float)NB));
            }
        }
    }
}

// ==================== launch (5 dispatches) ====================
extern "C" void kernel_launch(void* const* d_in, const int* in_sizes, int n_in,
                              void* d_out, int out_size, void* d_ws, size_t ws_size,
                              hipStream_t stream) {
    const float* vcross = (const float*)d_in[0];
    const float* tcross = (const float*)d_in[1];
    const float* vuni   = (const float*)d_in[2];
    const float* tuni   = (const float*)d_in[3];
    const float* W1     = (const float*)d_in[4];
    const float* b1     = (const float*)d_in[5];
    const float* W2     = (const float*)d_in[6];
    const float* b2     = (const float*)d_in[7];

    char* ws = (char*)d_ws;
    float* diag   = (float*)(ws + OFF_DIAG);
    int* neg      = (int*)(ws + OFF_NEG);
    int* mrows    = (int*)(ws + OFF_MROWS);
    float* acc    = (float*)(ws + OFF_ACC);
    int* mcount   = (int*)(ws + OFF_ACC + 4);
    int* hcount   = (int*)(ws + OFF_ACC + 8);
    ushort_t* bp1 = (ushort_t*)(ws + OFF_BP1);
    ushort_t* bp2 = (ushort_t*)(ws + OFF_BP2);
    unsigned long long* fb2 = (unsigned long long*)(ws + OFF_FB2);
    float* diag2  = (float*)(ws + OFF_DIAG2);
    ushort_t* A2  = (ushort_t*)(ws + OFF_A2);
    ushort_t* w1t = (ushort_t*)(ws + OFF_W1T);
    ushort_t* tb  = (ushort_t*)(ws + OFF_TB);
    ushort_t* vb  = (ushort_t*)(ws + OFF_VB);

    prep_uni_kernel<<<1056, 256, 0, stream>>>(tuni, vuni, W1, tb, vb, w1t, diag,
                                              (uint32_t*)(ws + OFF_ACC));
    mine_p1_kernel<<<dim3(64, NPART), 256, 0, stream>>>(tb, vb, diag, bp1);
    combine_p1_kernel<<<NB / 256, 256, 0, stream>>>(bp1, diag, tb, neg, mrows, mcount, A2, diag2);
    mine_p2_kernel<<<dim3(8, 64), 256, 0, stream>>>(A2, vb, diag2, mrows, mcount, bp2, fb2);
    head5_kernel<<<NB / 32, 256, 0, stream>>>(w1t, neg, bp2, fb2,
                                              tcross, vcross, W1, b1, W2, b2,
                                              acc, hcount, (float*)d_out);
}